// Round 14
// baseline (474.572 us; speedup 1.0000x reference)
//
#include <hip/hip_runtime.h>
#include <cstdint>
#include <cstddef>
#include <cmath>

#define DI __device__ __forceinline__

typedef __attribute__((ext_vector_type(2))) float f32x2;
typedef __attribute__((ext_vector_type(4))) float f32x4;
typedef __attribute__((ext_vector_type(4))) unsigned int u32x4;
typedef __attribute__((ext_vector_type(4))) unsigned short u16x4;

constexpr int B_ = 32, C_ = 384, N_ = 1024, HID2_ = 2304, QS_ = 1152;

DI unsigned short f2b(float f) {
  union { float f; unsigned int u; } v; v.f = f;
  unsigned int u = v.u;
  return (unsigned short)((u + 0x7FFFu + ((u >> 16) & 1u)) >> 16);
}
DI float b2f(unsigned short h) {
  union { unsigned int u; float f; } v; v.u = ((unsigned int)h) << 16;
  return v.f;
}
DI float sigmoid_f(float x) { return __builtin_amdgcn_rcpf(1.0f + __expf(-x)); }
// fast GELU: branch outputs scaled by gamma=1e-6 -> ~1e-8 abs error contribution
DI float gelu_f(float x) { return x * sigmoid_f(1.702f * x); }

DI void gload_lds16(const void* g, void* l) {
  __builtin_amdgcn_global_load_lds(
      (const __attribute__((address_space(1))) void*)g,
      (__attribute__((address_space(3))) void*)l, 16, 0, 0);
}

// ---------------- fp8 e4m3 (OCP) helpers; both branches are gamma=1e-6 scaled ----------------
#if __has_builtin(__builtin_amdgcn_cvt_pk_fp8_f32) && __has_builtin(__builtin_amdgcn_cvt_pk_f32_fp8)
#define HW_FP8 1
#else
#define HW_FP8 0
#endif

DI unsigned char f2e4_sw(float x) {
  float a = fabsf(x);
  unsigned char s = (x < 0.f) ? 0x80 : 0;
  if (!(a >= 0.0009765625f)) return s;
  if (a >= 448.f) return s | 0x7E;
  int e; float m = frexpf(a, &e);
  m *= 2.f; e -= 1;
  if (e < -6) {
    int q = (int)rintf(a * 512.f);
    if (q > 7) return s | 0x08;
    return s | (unsigned char)q;
  }
  int mi = (int)rintf((m - 1.f) * 8.f);
  if (mi == 8) { mi = 0; e += 1; }
  if (e > 8) return s | 0x7E;
  return s | (unsigned char)(((e + 7) << 3) | mi);
}
DI float e42f_sw(unsigned char h) {
  int e = (h >> 3) & 0xF, m = h & 7;
  float v;
  if (e == 0) v = (float)m * 0.001953125f;
  else { union { unsigned u; float f; } w; w.u = (unsigned)((e + 120) << 23) | ((unsigned)m << 20); v = w.f; }
  return (h & 0x80) ? -v : v;
}
DI unsigned char f2e4(float x) {
#if HW_FP8
  int r = __builtin_amdgcn_cvt_pk_fp8_f32(x, x, 0, false);
  return (unsigned char)(r & 0xFF);
#else
  return f2e4_sw(x);
#endif
}
DI unsigned int enc4(float a, float b, float c, float d) {
#if HW_FP8
  int r = 0;
  r = __builtin_amdgcn_cvt_pk_fp8_f32(a, b, r, false);
  r = __builtin_amdgcn_cvt_pk_fp8_f32(c, d, r, true);
  return (unsigned int)r;
#else
  return (unsigned)f2e4(a) | ((unsigned)f2e4(b) << 8) | ((unsigned)f2e4(c) << 16) | ((unsigned)f2e4(d) << 24);
#endif
}
DI void dec4(unsigned int v, float* o) {
#if HW_FP8
  f32x2 lo = __builtin_amdgcn_cvt_pk_f32_fp8((int)v, false);
  f32x2 hi = __builtin_amdgcn_cvt_pk_f32_fp8((int)v, true);
  o[0] = lo[0]; o[1] = lo[1]; o[2] = hi[0]; o[3] = hi[1];
#else
  o[0] = e42f_sw(v & 0xFF); o[1] = e42f_sw((v >> 8) & 0xFF);
  o[2] = e42f_sw((v >> 16) & 0xFF); o[3] = e42f_sw((v >> 24) & 0xFF);
#endif
}

// ---------------- one-shot prep: all weights -> fp8, dw transpose, bias concat, fourier ----------------
__global__ void prep_k(const float* __restrict__ q_w, const float* __restrict__ k_w,
    const float* __restrict__ vc_w, const float* __restrict__ pj_w,
    const float* __restrict__ w1, const float* __restrict__ w2,
    const float* __restrict__ dw_w, const float* __restrict__ mdw,
    const float* __restrict__ q_b, const float* __restrict__ k_b, const float* __restrict__ v_b,
    unsigned char* __restrict__ WQKV, unsigned char* __restrict__ WP,
    unsigned char* __restrict__ W1, unsigned char* __restrict__ W2,
    float* __restrict__ DT1, float* __restrict__ DT2,
    float* __restrict__ BQKV, float* __restrict__ feat) {
  int i = blockIdx.x * 256 + threadIdx.x;
  if (i < 442368) {                                    // WQKV (1152 x 384) fp8
    int o = i / 384, c = i % 384;
    float v = (o < 384) ? q_w[o * 384 + c] : (o < 768) ? k_w[(o - 384) * 384 + c]
                                                       : vc_w[(o - 768) * 384 + c];
    WQKV[i] = f2e4(v); return;
  }
  i -= 442368;
  if (i < 147456) { WP[i] = f2e4(pj_w[i]); return; }
  i -= 147456;
  if (i < 884736) { W1[i] = f2e4(w1[i]); return; }
  i -= 884736;
  if (i < 884736) { W2[i] = f2e4(w2[i]); return; }
  i -= 884736;
  if (i < 3456)  { int c = i / 9, k = i % 9; DT1[k * C_ + c] = dw_w[i]; return; }
  i -= 3456;
  if (i < 20736) { int c = i / 9, k = i % 9; DT2[k * HID2_ + c] = mdw[i]; return; }
  i -= 20736;
  if (i < 1152)  { BQKV[i] = (i < 384) ? q_b[i] : (i < 768) ? k_b[i - 384] : v_b[i - 768]; return; }
  i -= 1152;
  if (i < 65536) {                                     // fourier features (N x 64)
    int n = i >> 6, j = i & 63;
    int h = n >> 5, w = n & 31;
    const float scale = 6.283185307179586f;
    float e = (j < 32) ? (float)(h + 1) / (32.0f + 1e-6f) * scale
                       : (float)(w + 1) / (32.0f + 1e-6f) * scale;
    int jj = j & 31;
    float dt = powf(10000.0f, (float)(jj >> 1) * (1.0f / 16.0f));
    float arg = e / dt;
    feat[i] = (jj & 1) ? cosf(arg) : sinf(arg);
  }
}

// ---------------- pos[n][c] = feat[n][:] . pos_w[c][:] + pos_b[c] ----------------
__global__ __launch_bounds__(384) void pos_k(const float* __restrict__ feat,
    const float* __restrict__ pw, const float* __restrict__ pb, float* __restrict__ pos) {
  __shared__ float fs[64];
  int n = blockIdx.x, c = threadIdx.x;
  if (c < 64) fs[c] = feat[n * 64 + c];
  __syncthreads();
  float s = pb[c];
  #pragma unroll
  for (int j = 0; j < 64; ++j) s += fs[j] * pw[c * 64 + j];
  pos[(size_t)n * C_ + c] = s;
}

// ---------------- LayerNorm over C, input (B,C,N) f32, output (B,N,C) fp8 ----------------
template<int HASPOS>
__global__ __launch_bounds__(256) void ln_k(const float* __restrict__ xin,
    const float* __restrict__ pos, const float* __restrict__ lw,
    const float* __restrict__ lb, unsigned char* __restrict__ out8) {
  __shared__ float tile[C_ * 33];
  int bid = blockIdx.x;                 // B * (N/32)
  int b = bid >> 5, n0 = (bid & 31) << 5;
  int t = threadIdx.x;
  const float* xb = xin + (size_t)b * C_ * N_;
  #pragma unroll
  for (int i = 0; i < 48; ++i) {
    int f = t + 256 * i;
    int c = f >> 5, nn = f & 31;
    tile[c * 33 + nn] = xb[(size_t)c * N_ + n0 + nn];
  }
  __syncthreads();
  int wv = t >> 6, l = t & 63;
  for (int tk = 0; tk < 8; ++tk) {
    int tn = wv * 8 + tk;
    float v[6];
    #pragma unroll
    for (int i = 0; i < 6; ++i) {
      int c = l + 64 * i;
      float x = tile[c * 33 + tn];
      if (HASPOS) x += pos[(size_t)(n0 + tn) * C_ + c];
      v[i] = x;
    }
    float s = v[0] + v[1] + v[2] + v[3] + v[4] + v[5];
    #pragma unroll
    for (int m = 1; m < 64; m <<= 1) s += __shfl_xor(s, m);
    float mean = s * (1.0f / 384.0f);
    float q = 0.f;
    #pragma unroll
    for (int i = 0; i < 6; ++i) { float d = v[i] - mean; q += d * d; }
    #pragma unroll
    for (int m = 1; m < 64; m <<= 1) q += __shfl_xor(q, m);
    float rstd = rsqrtf(q * (1.0f / 384.0f) + 1e-6f);
    #pragma unroll
    for (int i = 0; i < 6; ++i) {
      int c = l + 64 * i;
      out8[((size_t)b * N_ + n0 + tn) * C_ + c] = f2e4((v[i] - mean) * rstd * lw[c] + lb[c]);
    }
  }
}

// ---------------- fp8 MFMA GEMM: out(M,O) = A(M,K) @ Wt(O,K)^T + bias ----------------
// BK=64 (32 KB LDS -> 4+ blocks/CU), both-sides XOR swizzle (64B rows, 4x16B slots),
// counted-vmcnt 2-phase staging. EPI 0: fp8 out. EPI 1: fp8 GELU out. EPI 2: bf16 out.
// EPI 0/1 use an LDS-repack epilogue: C-tile bytes -> LDS -> 4x dwordx4 coalesced stores.
template<int EPI>
__global__ __launch_bounds__(256) void gemm8_k(const unsigned char* __restrict__ A,
    const unsigned char* __restrict__ Wt, const float* __restrict__ bias,
    unsigned char* __restrict__ out8, unsigned short* __restrict__ outb,
    int K, int O) {
  __shared__ __align__(16) unsigned char As[2][128 * 64];   // 8 KB x2
  __shared__ __align__(16) unsigned char Bs[2][128 * 64];   // 8 KB x2 (32 KB total)
  const int gx = gridDim.x;
  const int nwg = gx * gridDim.y;
  const int lid = blockIdx.y * gx + blockIdx.x;
  const int chunk = nwg >> 3;
  const int swz = (lid & 7) * chunk + (lid >> 3);
  const int m0 = (swz / gx) * 128, n0 = (swz % gx) * 128;
  const int t = threadIdx.x, l = t & 63, wv = t >> 6;
  const int wr = wv >> 1, wc = wv & 1;
  const int fr = l & 15, fq = l >> 4;
  // staging: chunk ch=t (rows 0..63) and ch=256+t (rows 64..127); 4x16B slots per 64B row
  const int arow = t >> 2;                         // 0..63
  const int acsw = ((t & 3) ^ (arow & 3)) * 16;    // pre-swizzled 16B slot in 64B row
  const unsigned char* Ag = A + (size_t)(m0 + arow) * K + acsw;
  const unsigned char* Bg = Wt + (size_t)(n0 + arow) * K + acsw;
  f32x4 acc[4][4];
  #pragma unroll
  for (int i = 0; i < 4; ++i)
    #pragma unroll
    for (int j = 0; j < 4; ++j) acc[i][j] = f32x4{0.f, 0.f, 0.f, 0.f};

  auto stage = [&](int buf, int k0) {
    char* Ad = (char*)&As[buf][0] + wv * 1024;     // wave-uniform base; HW adds lane*16
    char* Bd = (char*)&Bs[buf][0] + wv * 1024;
    gload_lds16(Ag + k0, Ad);
    gload_lds16(Ag + (size_t)64 * K + k0, Ad + 4096);   // rows 64..127: (row&3) unchanged
    gload_lds16(Bg + k0, Bd);
    gload_lds16(Bg + (size_t)64 * K + k0, Bd + 4096);
  };

  const int nt = K >> 6;
  stage(0, 0);                                 // prologue: no wait
  for (int tt = 0; tt < nt; ++tt) {
    const int cur = tt & 1;
    if (tt + 1 < nt) {
      stage(cur ^ 1, (tt + 1) << 6);           // 4 more loads -> 8 in flight
      asm volatile("s_waitcnt vmcnt(4)" ::: "memory");   // cur's 4 landed (FIFO)
    } else {
      asm volatile("s_waitcnt vmcnt(0)" ::: "memory");
    }
    __builtin_amdgcn_s_barrier();              // cur staged for ALL waves
    #pragma unroll
    for (int kk = 0; kk < 2; ++kk) {
      const int slot = (kk << 1) | (fq >> 1);  // 16B slot 0..3
      const int sub = (fq & 1) << 3;           // 8B half
      long af[4], bfr[4];
      #pragma unroll
      for (int mi = 0; mi < 4; ++mi) {
        int row = wr * 64 + mi * 16 + fr;
        af[mi] = *(const long*)((const char*)&As[cur][0] + row * 64 +
                                ((slot ^ (row & 3)) << 4) + sub);
      }
      #pragma unroll
      for (int ni = 0; ni < 4; ++ni) {
        int row = wc * 64 + ni * 16 + fr;
        bfr[ni] = *(const long*)((const char*)&Bs[cur][0] + row * 64 +
                                 ((slot ^ (row & 3)) << 4) + sub);
      }
      #pragma unroll
      for (int mi = 0; mi < 4; ++mi)
        #pragma unroll
        for (int ni = 0; ni < 4; ++ni)
          acc[mi][ni] = __builtin_amdgcn_mfma_f32_16x16x32_fp8_fp8(af[mi], bfr[ni], acc[mi][ni], 0, 0, 0);
    }
    __builtin_amdgcn_s_barrier();              // all reads of cur consumed before restage
  }
  const int rb = fq * 4;
  if (EPI == 2) {
    #pragma unroll
    for (int mi = 0; mi < 4; ++mi)
      #pragma unroll
      for (int ni = 0; ni < 4; ++ni) {
        int col = n0 + wc * 64 + ni * 16 + fr;
        float bv = bias[col];
        #pragma unroll
        for (int j = 0; j < 4; ++j) {
          int row = m0 + wr * 64 + mi * 16 + rb + j;
          outb[(size_t)row * O + col] = f2b(acc[mi][ni][j] + bv);
        }
      }
  } else {
    // LDS-repack epilogue: As+Bs (32 KB) now dead; C-tile = 16 KB bytes
    unsigned char* ctile = (unsigned char*)&As[0][0];
    #pragma unroll
    for (int mi = 0; mi < 4; ++mi) {
      #pragma unroll
      for (int ni = 0; ni < 4; ++ni) {
        int lcol = wc * 64 + ni * 16 + fr;
        float bv = bias[n0 + lcol];
        #pragma unroll
        for (int j = 0; j < 4; ++j) {
          int lrow = wr * 64 + mi * 16 + rb + j;
          float val = acc[mi][ni][j] + bv;
          if (EPI == 1) val = gelu_f(val);
          ctile[lrow * 128 + lcol] = f2e4(val);
        }
      }
    }
    __builtin_amdgcn_s_barrier();
    const int row = t >> 1, off = (t & 1) * 64;
    const char* src = (const char*)ctile + row * 128 + off;
    unsigned char* dst = out8 + (size_t)(m0 + row) * O + n0 + off;
    #pragma unroll
    for (int q = 0; q < 4; ++q)
      *(u32x4*)(dst + q * 16) = *(const u32x4*)(src + q * 16);
  }
}

// ---------------- fp8 fc2 transposed: out[b,c,n] += g2[c]*(sum_k W2[c,k]*H2[b,n,k] + b2[c]) ----------------
__global__ __launch_bounds__(256) void fc2t8_k(const unsigned char* __restrict__ W2b,
    const unsigned char* __restrict__ H2, const float* __restrict__ b2,
    const float* __restrict__ g2, float* __restrict__ out, int bofs) {
  __shared__ __align__(16) unsigned char As[2][128 * 128];
  __shared__ __align__(16) unsigned char Bs[2][128 * 128];
  const int K = HID2_;
  const int nwg = 8 * gridDim.y;
  const int lid = blockIdx.y * 8 + blockIdx.x;
  const int chunk = nwg >> 3;
  const int swz = (lid & 7) * chunk + (lid >> 3);
  const int n0 = (swz & 7) * 128;
  const int y2 = swz >> 3;
  const int img = y2 / 3, m0 = (y2 % 3) * 128;
  const int t = threadIdx.x, l = t & 63, wv = t >> 6;
  const int wr = wv >> 1, wc = wv & 1;
  const int fr = l & 15, fq = l >> 4;
  const int arow = t >> 3;
  const int acsw = ((t & 7) ^ (arow & 7)) * 16;
  const unsigned char* Ag = W2b + (size_t)(m0 + arow) * K + acsw;
  const unsigned char* Bg = H2 + ((size_t)img * N_ + n0 + arow) * K + acsw;
  f32x4 acc[4][4];
  #pragma unroll
  for (int i = 0; i < 4; ++i)
    #pragma unroll
    for (int j = 0; j < 4; ++j) acc[i][j] = f32x4{0.f, 0.f, 0.f, 0.f};

  auto stage = [&](int buf, int k0) {
    char* Ad = (char*)&As[buf][0] + wv * 1024;
    char* Bd = (char*)&Bs[buf][0] + wv * 1024;
    #pragma unroll
    for (int s = 0; s < 4; ++s) {
      gload_lds16(Ag + (size_t)(s * 32) * K + k0, Ad + s * 4096);
      gload_lds16(Bg + (size_t)(s * 32) * K + k0, Bd + s * 4096);
    }
  };

  const int nt = K >> 7;                            // 18
  stage(0, 0);
  for (int tt = 0; tt < nt; ++tt) {
    const int cur = tt & 1;
    if (tt + 1 < nt) {
      stage(cur ^ 1, (tt + 1) << 7);
      asm volatile("s_waitcnt vmcnt(8)" ::: "memory");
    } else {
      asm volatile("s_waitcnt vmcnt(0)" ::: "memory");
    }
    __builtin_amdgcn_s_barrier();
    #pragma unroll
    for (int kk = 0; kk < 4; ++kk) {
      const int slot = (kk << 1) | (fq >> 1);
      const int sub = (fq & 1) << 3;
      long af[4], bfr[4];
      #pragma unroll
      for (int mi = 0; mi < 4; ++mi) {
        int row = wr * 64 + mi * 16 + fr;
        af[mi] = *(const long*)((const char*)&As[cur][0] + row * 128 +
                                ((slot ^ (row & 7)) << 4) + sub);
      }
      #pragma unroll
      for (int ni = 0; ni < 4; ++ni) {
        int row = wc * 64 + ni * 16 + fr;
        bfr[ni] = *(const long*)((const char*)&Bs[cur][0] + row * 128 +
                                 ((slot ^ (row & 7)) << 4) + sub);
      }
      #pragma unroll
      for (int mi = 0; mi < 4; ++mi)
        #pragma unroll
        for (int ni = 0; ni < 4; ++ni)
          acc[mi][ni] = __builtin_amdgcn_mfma_f32_16x16x32_fp8_fp8(af[mi], bfr[ni], acc[mi][ni], 0, 0, 0);
    }
    __builtin_amdgcn_s_barrier();
  }
  const int rb = fq * 4;
  const size_t obase = ((size_t)(img + bofs) * C_) << 10;
  #pragma unroll
  for (int mi = 0; mi < 4; ++mi) {
    #pragma unroll
    for (int j = 0; j < 4; ++j) {
      int row = m0 + wr * 64 + mi * 16 + rb + j;
      float bv = b2[row], gv = g2[row];
      #pragma unroll
      for (int ni = 0; ni < 4; ++ni) {
        int col = n0 + wc * 64 + ni * 16 + fr;
        size_t oi = obase + ((size_t)row << 10) + col;
        out[oi] = out[oi] + gv * (acc[mi][ni][j] + bv);
      }
    }
  }
}

// ---------------- fused gram + l2norm + temp-scale + softmax -> attn fp8 (B,6,64,64) ----------------
__global__ __launch_bounds__(256) void attn_k(const unsigned char* __restrict__ qkv,
    const float* __restrict__ temp, unsigned char* __restrict__ attn8) {
  __shared__ __align__(16) float Qs[32][68];
  __shared__ __align__(16) float Ks[32][68];
  __shared__ float qinv_s[64], kinv_s[64];
  const int bid = blockIdx.x;           // B*6
  const int b = bid / 6, h = bid % 6;
  const int t = threadIdx.x;
  const unsigned char* qb = qkv + (size_t)b * N_ * QS_ + h * 64;
  const unsigned char* kb = qb + 384;
  const int li = t >> 4, ld = (t & 15) * 4;
  const int d0 = (t >> 4) * 4, e0 = (t & 15) * 4;
  float acc[4][4] = {};
  float ssq = 0.0f;
  for (int n0 = 0; n0 < N_; n0 += 32) {
    __syncthreads();
    #pragma unroll
    for (int rr = 0; rr < 2; ++rr) {
      int i = li + rr * 16;
      unsigned int qv = *(const unsigned int*)(qb + (size_t)(n0 + i) * QS_ + ld);
      unsigned int kv = *(const unsigned int*)(kb + (size_t)(n0 + i) * QS_ + ld);
      float qd[4], kd[4];
      dec4(qv, qd); dec4(kv, kd);
      #pragma unroll
      for (int j = 0; j < 4; ++j) { Qs[i][ld + j] = qd[j]; Ks[i][ld + j] = kd[j]; }
    }
    __syncthreads();
    if (t < 64) {
      #pragma unroll
      for (int i = 0; i < 32; ++i) { float x = Qs[i][t]; ssq += x * x; }
    } else if (t < 128) {
      #pragma unroll
      for (int i = 0; i < 32; ++i) { float x = Ks[i][t - 64]; ssq += x * x; }
    }
    #pragma unroll
    for (int i = 0; i < 32; ++i) {
      f32x4 qv = *(const f32x4*)&Qs[i][d0];
      f32x4 kv = *(const f32x4*)&Ks[i][e0];
      #pragma unroll
      for (int di = 0; di < 4; ++di)
        #pragma unroll
        for (int ei = 0; ei < 4; ++ei) acc[di][ei] += qv[di] * kv[ei];
    }
  }
  if (t < 64) { float nr = sqrtf(ssq); qinv_s[t] = 1.0f / fmaxf(nr, 1e-12f); }
  else if (t < 128) { float nr = sqrtf(ssq); kinv_s[t - 64] = 1.0f / fmaxf(nr, 1e-12f); }
  __syncthreads();
  const float tp = temp[h];
  #pragma unroll
  for (int di = 0; di < 4; ++di) {
    int d = d0 + di;
    float vals[4];
    #pragma unroll
    for (int ei = 0; ei < 4; ++ei) vals[ei] = acc[di][ei] * qinv_s[d] * kinv_s[e0 + ei] * tp;
    float mx = fmaxf(fmaxf(vals[0], vals[1]), fmaxf(vals[2], vals[3]));
    #pragma unroll
    for (int m = 1; m < 16; m <<= 1) mx = fmaxf(mx, __shfl_xor(mx, m));
    float ex[4], s = 0.f;
    #pragma unroll
    for (int ei = 0; ei < 4; ++ei) { ex[ei] = __expf(vals[ei] - mx); s += ex[ei]; }
    #pragma unroll
    for (int m = 1; m < 16; m <<= 1) s += __shfl_xor(s, m);
    float inv = __builtin_amdgcn_rcpf(s);
    unsigned int ov = enc4(ex[0] * inv, ex[1] * inv, ex[2] * inv, ex[3] * inv);
    *(unsigned int*)(attn8 + ((size_t)(b * 6 + h) * 64 + d) * 64 + e0) = ov;
  }
}

// ---------------- dwconv3x3 + BN + SiLU, times vc -> v (fp8), 4ch x 4w per thread ----------------
__global__ __launch_bounds__(192) void dwconv1_k(const unsigned char* __restrict__ xn,
    const float* __restrict__ dwt, const float* __restrict__ dwb,
    const float* __restrict__ bng, const float* __restrict__ bnb,
    const float* __restrict__ bnm, const float* __restrict__ bnv,
    unsigned char* __restrict__ qkv) {
  const int c0 = threadIdx.x * 4;                 // [0,384)
  const int h = blockIdx.y >> 2;
  const int w0 = (blockIdx.y & 3) * 8 + threadIdx.y * 4;
  const int b = blockIdx.z;
  const unsigned char* xb = xn + ((size_t)b * N_ + h * 32) * C_ + c0;
  f32x4 acc[4] = {};
  #pragma unroll
  for (int dy = -1; dy <= 1; ++dy) {
    int hh = h + dy;
    if (hh < 0 || hh >= 32) continue;
    f32x4 xf[6];
    #pragma unroll
    for (int j = 0; j < 6; ++j) {
      int ww = w0 - 1 + j;
      if (ww >= 0 && ww < 32) {
        unsigned int xv = *(const unsigned int*)(xb + (dy * 32 + ww) * C_);
        float d4[4]; dec4(xv, d4);
        xf[j] = f32x4{d4[0], d4[1], d4[2], d4[3]};
      } else xf[j] = f32x4{0.f, 0.f, 0.f, 0.f};
    }
    #pragma unroll
    for (int dx = 0; dx < 3; ++dx) {
      f32x4 wv = *(const f32x4*)(dwt + ((dy + 1) * 3 + dx) * C_ + c0);
      #pragma unroll
      for (int px = 0; px < 4; ++px)
        #pragma unroll
        for (int j = 0; j < 4; ++j) acc[px][j] += xf[dx + px][j] * wv[j];
    }
  }
  f32x4 dbv = *(const f32x4*)(dwb + c0);
  f32x4 mv = *(const f32x4*)(bnm + c0);
  f32x4 vv = *(const f32x4*)(bnv + c0);
  f32x4 gv = *(const f32x4*)(bng + c0);
  f32x4 bv = *(const f32x4*)(bnb + c0);
  f32x4 rs;
  #pragma unroll
  for (int j = 0; j < 4; ++j) rs[j] = rsqrtf(vv[j] + 1e-5f);
  unsigned char* vb = qkv + ((size_t)b * N_ + h * 32 + w0) * QS_ + 768 + c0;
  #pragma unroll
  for (int px = 0; px < 4; ++px) {
    unsigned int vcv = *(const unsigned int*)(vb + px * QS_);
    float vd[4]; dec4(vcv, vd);
    float o4[4];
    #pragma unroll
    for (int j = 0; j < 4; ++j) {
      float u = (acc[px][j] + dbv[j] - mv[j]) * rs[j] * gv[j] + bv[j];
      float si = u * sigmoid_f(u);
      o4[j] = si * vd[j];
    }
    *(unsigned int*)(vb + px * QS_) = enc4(o4[0], o4[1], o4[2], o4[3]);
  }
}

// ---------------- xo[b,n,h*64+d] = sum_e attn[b,h,d,e] * v[b,n,h*64+e] (fp8 MFMA) ----------------
__global__ __launch_bounds__(256) void xo_k(const unsigned char* __restrict__ qkv,
    const unsigned char* __restrict__ attn, unsigned char* __restrict__ xo) {
  const int bid = blockIdx.x;           // B*6*16
  const int b = bid / 96, r = bid % 96, h = r / 16, m0 = (r % 16) * 64;
  const int t = threadIdx.x, wv = t >> 6, l = t & 63;
  const int n0 = m0 + wv * 16;
  const int fr = l & 15, fq = l >> 4;
  const unsigned char* vb = qkv + (size_t)b * N_ * QS_ + 768 + h * 64;
  const unsigned char* ab = attn + (size_t)(b * 6 + h) * 4096;
  f32x4 acc[4];
  #pragma unroll
  for (int i = 0; i < 4; ++i) acc[i] = f32x4{0.f, 0.f, 0.f, 0.f};
  #pragma unroll
  for (int k0 = 0; k0 < 64; k0 += 32) {
    long af = *(const long*)(vb + (size_t)(n0 + fr) * QS_ + k0 + fq * 8);
    #pragma unroll
    for (int ni = 0; ni < 4; ++ni) {
      long bfr = *(const long*)(ab + (ni * 16 + fr) * 64 + k0 + fq * 8);
      acc[ni] = __builtin_amdgcn_mfma_f32_16x16x32_fp8_fp8(af, bfr, acc[ni], 0, 0, 0);
    }
  }
  const int rb = fq * 4;
  #pragma unroll
  for (int ni = 0; ni < 4; ++ni)
    #pragma unroll
    for (int j = 0; j < 4; ++j) {
      int row = n0 + rb + j;
      xo[((size_t)b * N_ + row) * C_ + h * 64 + ni * 16 + fr] = f2e4(acc[ni][j]);
    }
}

// ---------------- faithful swapaxes residual: out = x + scramble(gamma1*y), f32 NCHW ----------------
__global__ __launch_bounds__(256) void resid1_k(const float* __restrict__ x,
    const unsigned short* __restrict__ y, const float* __restrict__ g1,
    float* __restrict__ xnew) {
  __shared__ unsigned short yp[32][36];
  __shared__ float g1s[32];
  const int bid = blockIdx.x;           // B*C
  const int b = bid / C_, c2 = bid % C_;
  const int hsrc = c2 / 12, cs0 = (c2 % 12) * 32;
  const int t = threadIdx.x;
  {
    int wq = t >> 3, h4 = (t & 7) * 4;
    u16x4 vv = *(const u16x4*)(y + ((size_t)b * N_ + hsrc * 32 + wq) * C_ + cs0 + h4);
    *(u16x4*)&yp[wq][h4] = vv;          // yp[w][h2]
  }
  if (t < 32) g1s[t] = g1[cs0 + t];
  __syncthreads();
  int h2 = t >> 3, w0 = (t & 7) * 4;
  size_t base = (((size_t)b * C_ + c2) << 10) + h2 * 32 + w0;
  f32x4 xv = *(const f32x4*)(x + base);
  f32x4 ov;
  #pragma unroll
  for (int i = 0; i < 4; ++i) ov[i] = xv[i] + g1s[h2] * b2f(yp[w0 + i][h2]);
  *(f32x4*)(xnew + base) = ov;
}

// ---------------- dwconv3x3 (hid) + GELU, fp8 in/out, 4ch x 4w per thread ----------------
__global__ __launch_bounds__(192) void dwconv2_k(const unsigned char* __restrict__ h1,
    const float* __restrict__ dwt, const float* __restrict__ dwb,
    unsigned char* __restrict__ h2) {
  const int c0 = (blockIdx.x * 192 + threadIdx.x) * 4;   // < 2304
  const int h = blockIdx.y >> 3, w0 = (blockIdx.y & 7) * 4;
  const int b = blockIdx.z;
  const unsigned char* xb = h1 + ((size_t)b * N_ + h * 32) * HID2_ + c0;
  f32x4 acc[4] = {};
  #pragma unroll
  for (int dy = -1; dy <= 1; ++dy) {
    int hh = h + dy;
    if (hh < 0 || hh >= 32) continue;
    f32x4 xf[6];
    #pragma unroll
    for (int j = 0; j < 6; ++j) {
      int ww = w0 - 1 + j;
      if (ww >= 0 && ww < 32) {
        unsigned int xv = *(const unsigned int*)(xb + (dy * 32 + ww) * HID2_);
        float d4[4]; dec4(xv, d4);
        xf[j] = f32x4{d4[0], d4[1], d4[2], d4[3]};
      } else xf[j] = f32x4{0.f, 0.f, 0.f, 0.f};
    }
    #pragma unroll
    for (int dx = 0; dx < 3; ++dx) {
      f32x4 wv = *(const f32x4*)(dwt + ((dy + 1) * 3 + dx) * HID2_ + c0);
      #pragma unroll
      for (int px = 0; px < 4; ++px)
        #pragma unroll
        for (int j = 0; j < 4; ++j) acc[px][j] += xf[dx + px][j] * wv[j];
    }
  }
  f32x4 dbv = *(const f32x4*)(dwb + c0);
  unsigned char* ob = h2 + ((size_t)b * N_ + h * 32 + w0) * HID2_ + c0;
  #pragma unroll
  for (int px = 0; px < 4; ++px) {
    unsigned int ov = enc4(gelu_f(acc[px][0] + dbv[0]), gelu_f(acc[px][1] + dbv[1]),
                           gelu_f(acc[px][2] + dbv[2]), gelu_f(acc[px][3] + dbv[3]));
    *(unsigned int*)(ob + px * HID2_) = ov;
  }
}

// ================================================================
extern "C" void kernel_launch(void* const* d_in, const int* in_sizes, int n_in,
                              void* d_out, int out_size, void* d_ws, size_t ws_size,
                              hipStream_t stream) {
  (void)in_sizes; (void)n_in; (void)out_size;
  const float* x    = (const float*)d_in[0];
  const float* posw = (const float*)d_in[1];
  const float* posb = (const float*)d_in[2];
  const float* ln1w = (const float*)d_in[3];
  const float* ln1b = (const float*)d_in[4];
  const float* q_w  = (const float*)d_in[5];
  const float* q_b  = (const float*)d_in[6];
  const float* k_w  = (const float*)d_in[7];
  const float* k_b  = (const float*)d_in[8];
  const float* v_w  = (const float*)d_in[9];
  const float* v_b  = (const float*)d_in[10];
  const float* dw_w = (const float*)d_in[11];
  const float* dw_b = (const float*)d_in[12];
  const float* bn_g = (const float*)d_in[13];
  const float* bn_b = (const float*)d_in[14];
  const float* bn_m = (const float*)d_in[15];
  const float* bn_v = (const float*)d_in[16];
  const float* temp = (const float*)d_in[17];
  const float* pj_w = (const float*)d_in[18];
  const float* pj_b = (const float*)d_in[19];
  const float* g1   = (const float*)d_in[20];
  const float* ln2w = (const float*)d_in[21];
  const float* ln2b = (const float*)d_in[22];
  const float* w1   = (const float*)d_in[23];
  const float* b1   = (const float*)d_in[24];
  const float* mdw  = (const float*)d_in[25];
  const float* mdb  = (const float*)d_in[26];
  const float* w2   = (const float*)d_in[27];
  const float* b2   = (const float*)d_in[28];
  const float* g2   = (const float*)d_in[29];
  float* out = (float*)d_out;           // also serves as XNEW (f32 B,C,H,W residual)

  char* ws = (char*)d_ws;
  size_t off = 0;
  auto alloc = [&](size_t bytes) { size_t o = off; off += (bytes + 255) & ~(size_t)255; return o; };
  const size_t TOK = (size_t)B_ * N_;            // 32768

  size_t oWQKV = alloc(442368), oWP = alloc(147456);        // fp8
  size_t oW1 = alloc(884736), oW2 = alloc(884736);          // fp8
  size_t oDT1 = alloc(9 * C_ * 4), oDT2 = alloc(9 * HID2_ * 4);
  size_t oBQKV = alloc(1152 * 4);
  size_t oFEAT = alloc(65536 * 4);
  size_t oPOS  = alloc((size_t)N_ * C_ * 4);
  size_t oATT  = alloc((size_t)B_ * 6 * 4096);              // fp8
  size_t oXN2  = alloc(TOK * C_);                // fp8 xn2 (survives into MLP)
  size_t oQKV  = alloc(TOK * QS_);               // fp8 37.7 MB -- dead before MLP
  size_t oXN = alloc(TOK * C_);                  // fp8 xn
  size_t oSC = alloc(TOK * C_);                  // fp8 xo
  size_t oSA = alloc(TOK * C_ * 2);              // bf16 y (proj out)

  // MLP H1/H2 (fp8) overlay the dead QKV+XN+SC+SA region plus remaining workspace.
  const size_t perImg = (size_t)N_ * HID2_;      // 2,359,296 B (fp8)
  size_t avail = (ws_size > oQKV + 512) ? (ws_size - oQKV - 512) : 0;
  int CH = (int)(avail / (2 * perImg));
  if (CH < 1) CH = 1;
  if (CH > 32) CH = 32;
  size_t oH1 = oQKV;
  size_t oH2 = oQKV + (size_t)CH * perImg;

  unsigned char* WQKV = (unsigned char*)(ws + oWQKV);
  unsigned char* WP = (unsigned char*)(ws + oWP);
  unsigned char* W1 = (unsigned char*)(ws + oW1);
  unsigned char* W2 = (unsigned char*)(ws + oW2);
  float* DT1 = (float*)(ws + oDT1);
  float* DT2 = (float*)(ws + oDT2);
  float* BQKV = (float*)(ws + oBQKV);
  float* FEAT = (float*)(ws + oFEAT);
  float* POS  = (float*)(ws + oPOS);
  unsigned char* ATT = (unsigned char*)(ws + oATT);
  unsigned char* XN2 = (unsigned char*)(ws + oXN2);
  unsigned char* QKV = (unsigned char*)(ws + oQKV);
  unsigned char* XN = (unsigned char*)(ws + oXN);
  unsigned char* SC = (unsigned char*)(ws + oSC);
  unsigned short* SA = (unsigned short*)(ws + oSA);
  unsigned char* H1 = (unsigned char*)(ws + oH1);
  unsigned char* H2 = (unsigned char*)(ws + oH2);

  // one-shot prep (weights, transposes, biases, fourier)
  prep_k<<<9571, 256, 0, stream>>>(q_w, k_w, v_w, pj_w, w1, w2, dw_w, mdw,
                                   q_b, k_b, v_b, WQKV, WP, W1, W2, DT1, DT2, BQKV, FEAT);
  pos_k<<<1024, 384, 0, stream>>>(FEAT, posw, posb, POS);
  // LN1 (x + pos) -> XN fp8
  ln_k<1><<<1024, 256, 0, stream>>>(x, POS, ln1w, ln1b, XN);
  // fused q|k|vc projection (fp8) -> QKV fp8
  gemm8_k<0><<<dim3(9, 256), 256, 0, stream>>>(XN, WQKV, BQKV, QKV, nullptr, 384, 1152);
  // gram + l2norm + softmax -> ATT fp8
  attn_k<<<192, 256, 0, stream>>>(QKV, temp, ATT);
  // v = silu(bn(dwconv(xn))) * vc, in place in QKV cols 768..
  dwconv1_k<<<dim3(1, 128, 32), dim3(96, 2), 0, stream>>>(XN, DT1, dw_b, bn_g, bn_b, bn_m, bn_v, QKV);
  // xo = attn @ v -> SC fp8
  xo_k<<<3072, 256, 0, stream>>>(QKV, ATT, SC);
  // proj (fp8) -> SA bf16 (xn dead)
  gemm8_k<2><<<dim3(3, 256), 256, 0, stream>>>(SC, WP, pj_b, nullptr, SA, 384, 384);
  // residual 1 with swapaxes scramble -> out (f32 NCHW)
  resid1_k<<<12288, 256, 0, stream>>>(x, SA, g1, out);
  // LN2 (reads out) -> XN2 fp8 (QKV/XN/SC/SA now dead)
  ln_k<0><<<1024, 256, 0, stream>>>(out, nullptr, ln2w, ln2b, XN2);
  // MLP branch (all fp8), chunked over batch
  for (int b0 = 0; b0 < B_; b0 += CH) {
    int cb = (b0 + CH <= B_) ? CH : (B_ - b0);
    const unsigned char* xn2c = XN2 + (size_t)b0 * N_ * C_;
    gemm8_k<1><<<dim3(18, cb * 8), 256, 0, stream>>>(xn2c, W1, b1, H1, nullptr, 384, 2304);
    dwconv2_k<<<dim3(3, 256, cb), 192, 0, stream>>>(H1, DT2, mdb, H2);
    fc2t8_k<<<dim3(8, 3 * cb), 256, 0, stream>>>(W2, H2, b2, g2, out, b0);
  }
}

// Round 15
// 462.990 us; speedup vs baseline: 1.0250x; 1.0250x over previous
//
#include <hip/hip_runtime.h>
#include <cstdint>
#include <cstddef>
#include <cmath>

#define DI __device__ __forceinline__

typedef __attribute__((ext_vector_type(2))) float f32x2;
typedef __attribute__((ext_vector_type(4))) float f32x4;
typedef __attribute__((ext_vector_type(4))) unsigned int u32x4;
typedef __attribute__((ext_vector_type(4))) unsigned short u16x4;

constexpr int B_ = 32, C_ = 384, N_ = 1024, HID2_ = 2304, QS_ = 1152;

DI unsigned short f2b(float f) {
  union { float f; unsigned int u; } v; v.f = f;
  unsigned int u = v.u;
  return (unsigned short)((u + 0x7FFFu + ((u >> 16) & 1u)) >> 16);
}
DI float b2f(unsigned short h) {
  union { unsigned int u; float f; } v; v.u = ((unsigned int)h) << 16;
  return v.f;
}
DI float sigmoid_f(float x) { return __builtin_amdgcn_rcpf(1.0f + __expf(-x)); }
// fast GELU: branch outputs scaled by gamma=1e-6 -> ~1e-8 abs error contribution
DI float gelu_f(float x) { return x * sigmoid_f(1.702f * x); }

DI void gload_lds16(const void* g, void* l) {
  __builtin_amdgcn_global_load_lds(
      (const __attribute__((address_space(1))) void*)g,
      (__attribute__((address_space(3))) void*)l, 16, 0, 0);
}

// ---------------- fp8 e4m3 (OCP) helpers; both branches are gamma=1e-6 scaled ----------------
#if __has_builtin(__builtin_amdgcn_cvt_pk_fp8_f32) && __has_builtin(__builtin_amdgcn_cvt_pk_f32_fp8)
#define HW_FP8 1
#else
#define HW_FP8 0
#endif

DI unsigned char f2e4_sw(float x) {
  float a = fabsf(x);
  unsigned char s = (x < 0.f) ? 0x80 : 0;
  if (!(a >= 0.0009765625f)) return s;
  if (a >= 448.f) return s | 0x7E;
  int e; float m = frexpf(a, &e);
  m *= 2.f; e -= 1;
  if (e < -6) {
    int q = (int)rintf(a * 512.f);
    if (q > 7) return s | 0x08;
    return s | (unsigned char)q;
  }
  int mi = (int)rintf((m - 1.f) * 8.f);
  if (mi == 8) { mi = 0; e += 1; }
  if (e > 8) return s | 0x7E;
  return s | (unsigned char)(((e + 7) << 3) | mi);
}
DI float e42f_sw(unsigned char h) {
  int e = (h >> 3) & 0xF, m = h & 7;
  float v;
  if (e == 0) v = (float)m * 0.001953125f;
  else { union { unsigned u; float f; } w; w.u = (unsigned)((e + 120) << 23) | ((unsigned)m << 20); v = w.f; }
  return (h & 0x80) ? -v : v;
}
DI unsigned char f2e4(float x) {
#if HW_FP8
  int r = __builtin_amdgcn_cvt_pk_fp8_f32(x, x, 0, false);
  return (unsigned char)(r & 0xFF);
#else
  return f2e4_sw(x);
#endif
}
DI unsigned int enc4(float a, float b, float c, float d) {
#if HW_FP8
  int r = 0;
  r = __builtin_amdgcn_cvt_pk_fp8_f32(a, b, r, false);
  r = __builtin_amdgcn_cvt_pk_fp8_f32(c, d, r, true);
  return (unsigned int)r;
#else
  return (unsigned)f2e4(a) | ((unsigned)f2e4(b) << 8) | ((unsigned)f2e4(c) << 16) | ((unsigned)f2e4(d) << 24);
#endif
}
DI void dec4(unsigned int v, float* o) {
#if HW_FP8
  f32x2 lo = __builtin_amdgcn_cvt_pk_f32_fp8((int)v, false);
  f32x2 hi = __builtin_amdgcn_cvt_pk_f32_fp8((int)v, true);
  o[0] = lo[0]; o[1] = lo[1]; o[2] = hi[0]; o[3] = hi[1];
#else
  o[0] = e42f_sw(v & 0xFF); o[1] = e42f_sw((v >> 8) & 0xFF);
  o[2] = e42f_sw((v >> 16) & 0xFF); o[3] = e42f_sw((v >> 24) & 0xFF);
#endif
}

// ---------------- one-shot prep: all weights -> fp8, dw transpose, bias concat, fourier ----------------
__global__ void prep_k(const float* __restrict__ q_w, const float* __restrict__ k_w,
    const float* __restrict__ vc_w, const float* __restrict__ pj_w,
    const float* __restrict__ w1, const float* __restrict__ w2,
    const float* __restrict__ dw_w, const float* __restrict__ mdw,
    const float* __restrict__ q_b, const float* __restrict__ k_b, const float* __restrict__ v_b,
    unsigned char* __restrict__ WQKV, unsigned char* __restrict__ WP,
    unsigned char* __restrict__ W1, unsigned char* __restrict__ W2,
    float* __restrict__ DT1, float* __restrict__ DT2,
    float* __restrict__ BQKV, float* __restrict__ feat) {
  int i = blockIdx.x * 256 + threadIdx.x;
  if (i < 442368) {                                    // WQKV (1152 x 384) fp8
    int o = i / 384, c = i % 384;
    float v = (o < 384) ? q_w[o * 384 + c] : (o < 768) ? k_w[(o - 384) * 384 + c]
                                                       : vc_w[(o - 768) * 384 + c];
    WQKV[i] = f2e4(v); return;
  }
  i -= 442368;
  if (i < 147456) { WP[i] = f2e4(pj_w[i]); return; }
  i -= 147456;
  if (i < 884736) { W1[i] = f2e4(w1[i]); return; }
  i -= 884736;
  if (i < 884736) { W2[i] = f2e4(w2[i]); return; }
  i -= 884736;
  if (i < 3456)  { int c = i / 9, k = i % 9; DT1[k * C_ + c] = dw_w[i]; return; }
  i -= 3456;
  if (i < 20736) { int c = i / 9, k = i % 9; DT2[k * HID2_ + c] = mdw[i]; return; }
  i -= 20736;
  if (i < 1152)  { BQKV[i] = (i < 384) ? q_b[i] : (i < 768) ? k_b[i - 384] : v_b[i - 768]; return; }
  i -= 1152;
  if (i < 65536) {                                     // fourier features (N x 64)
    int n = i >> 6, j = i & 63;
    int h = n >> 5, w = n & 31;
    const float scale = 6.283185307179586f;
    float e = (j < 32) ? (float)(h + 1) / (32.0f + 1e-6f) * scale
                       : (float)(w + 1) / (32.0f + 1e-6f) * scale;
    int jj = j & 31;
    float dt = powf(10000.0f, (float)(jj >> 1) * (1.0f / 16.0f));
    float arg = e / dt;
    feat[i] = (jj & 1) ? cosf(arg) : sinf(arg);
  }
}

// ---------------- pos[n][c] = feat[n][:] . pos_w[c][:] + pos_b[c] ----------------
__global__ __launch_bounds__(384) void pos_k(const float* __restrict__ feat,
    const float* __restrict__ pw, const float* __restrict__ pb, float* __restrict__ pos) {
  __shared__ float fs[64];
  int n = blockIdx.x, c = threadIdx.x;
  if (c < 64) fs[c] = feat[n * 64 + c];
  __syncthreads();
  float s = pb[c];
  #pragma unroll
  for (int j = 0; j < 64; ++j) s += fs[j] * pw[c * 64 + j];
  pos[(size_t)n * C_ + c] = s;
}

// ---------------- LayerNorm over C, input (B,C,N) f32, output (B,N,C) fp8 ----------------
template<int HASPOS>
__global__ __launch_bounds__(256) void ln_k(const float* __restrict__ xin,
    const float* __restrict__ pos, const float* __restrict__ lw,
    const float* __restrict__ lb, unsigned char* __restrict__ out8) {
  __shared__ float tile[C_ * 33];
  int bid = blockIdx.x;                 // B * (N/32)
  int b = bid >> 5, n0 = (bid & 31) << 5;
  int t = threadIdx.x;
  const float* xb = xin + (size_t)b * C_ * N_;
  #pragma unroll
  for (int i = 0; i < 48; ++i) {
    int f = t + 256 * i;
    int c = f >> 5, nn = f & 31;
    tile[c * 33 + nn] = xb[(size_t)c * N_ + n0 + nn];
  }
  __syncthreads();
  int wv = t >> 6, l = t & 63;
  for (int tk = 0; tk < 8; ++tk) {
    int tn = wv * 8 + tk;
    float v[6];
    #pragma unroll
    for (int i = 0; i < 6; ++i) {
      int c = l + 64 * i;
      float x = tile[c * 33 + tn];
      if (HASPOS) x += pos[(size_t)(n0 + tn) * C_ + c];
      v[i] = x;
    }
    float s = v[0] + v[1] + v[2] + v[3] + v[4] + v[5];
    #pragma unroll
    for (int m = 1; m < 64; m <<= 1) s += __shfl_xor(s, m);
    float mean = s * (1.0f / 384.0f);
    float q = 0.f;
    #pragma unroll
    for (int i = 0; i < 6; ++i) { float d = v[i] - mean; q += d * d; }
    #pragma unroll
    for (int m = 1; m < 64; m <<= 1) q += __shfl_xor(q, m);
    float rstd = rsqrtf(q * (1.0f / 384.0f) + 1e-6f);
    #pragma unroll
    for (int i = 0; i < 6; ++i) {
      int c = l + 64 * i;
      out8[((size_t)b * N_ + n0 + tn) * C_ + c] = f2e4((v[i] - mean) * rstd * lw[c] + lb[c]);
    }
  }
}

// ---------------- fp8 MFMA GEMM: out(M,O) = A(M,K) @ Wt(O,K)^T + bias ----------------
// BK=128 (proven R13 body: 128B rows, 8x16B slots, both-sides XOR swizzle, counted vmcnt).
// EPI 0: fp8 out. EPI 1: fp8 GELU out. EPI 2: bf16 out.
// NEW vs R13: EPI 0/1 use LDS-repack epilogue (C bytes -> LDS -> 2x dwordx4 stores/thread).
template<int EPI>
__global__ __launch_bounds__(256) void gemm8_k(const unsigned char* __restrict__ A,
    const unsigned char* __restrict__ Wt, const float* __restrict__ bias,
    unsigned char* __restrict__ out8, unsigned short* __restrict__ outb,
    int K, int O) {
  __shared__ __align__(16) unsigned char As[2][128 * 128];
  __shared__ __align__(16) unsigned char Bs[2][128 * 128];
  const int gx = gridDim.x;
  const int nwg = gx * gridDim.y;
  const int lid = blockIdx.y * gx + blockIdx.x;
  const int chunk = nwg >> 3;
  const int swz = (lid & 7) * chunk + (lid >> 3);
  const int m0 = (swz / gx) * 128, n0 = (swz % gx) * 128;
  const int t = threadIdx.x, l = t & 63, wv = t >> 6;
  const int wr = wv >> 1, wc = wv & 1;
  const int fr = l & 15, fq = l >> 4;
  const int arow = t >> 3;
  const int acsw = ((t & 7) ^ (arow & 7)) * 16;
  const unsigned char* Ag = A + (size_t)(m0 + arow) * K + acsw;
  const unsigned char* Bg = Wt + (size_t)(n0 + arow) * K + acsw;
  f32x4 acc[4][4];
  #pragma unroll
  for (int i = 0; i < 4; ++i)
    #pragma unroll
    for (int j = 0; j < 4; ++j) acc[i][j] = f32x4{0.f, 0.f, 0.f, 0.f};

  auto stage = [&](int buf, int k0) {
    char* Ad = (char*)&As[buf][0] + wv * 1024;
    char* Bd = (char*)&Bs[buf][0] + wv * 1024;
    #pragma unroll
    for (int s = 0; s < 4; ++s) {
      gload_lds16(Ag + (size_t)(s * 32) * K + k0, Ad + s * 4096);
      gload_lds16(Bg + (size_t)(s * 32) * K + k0, Bd + s * 4096);
    }
  };

  const int nt = K >> 7;
  stage(0, 0);
  for (int tt = 0; tt < nt; ++tt) {
    const int cur = tt & 1;
    if (tt + 1 < nt) {
      stage(cur ^ 1, (tt + 1) << 7);
      asm volatile("s_waitcnt vmcnt(8)" ::: "memory");
    } else {
      asm volatile("s_waitcnt vmcnt(0)" ::: "memory");
    }
    __builtin_amdgcn_s_barrier();
    #pragma unroll
    for (int kk = 0; kk < 4; ++kk) {
      const int slot = (kk << 1) | (fq >> 1);
      const int sub = (fq & 1) << 3;
      long af[4], bfr[4];
      #pragma unroll
      for (int mi = 0; mi < 4; ++mi) {
        int row = wr * 64 + mi * 16 + fr;
        af[mi] = *(const long*)((const char*)&As[cur][0] + row * 128 +
                                ((slot ^ (row & 7)) << 4) + sub);
      }
      #pragma unroll
      for (int ni = 0; ni < 4; ++ni) {
        int row = wc * 64 + ni * 16 + fr;
        bfr[ni] = *(const long*)((const char*)&Bs[cur][0] + row * 128 +
                                 ((slot ^ (row & 7)) << 4) + sub);
      }
      #pragma unroll
      for (int mi = 0; mi < 4; ++mi)
        #pragma unroll
        for (int ni = 0; ni < 4; ++ni)
          acc[mi][ni] = __builtin_amdgcn_mfma_f32_16x16x32_fp8_fp8(af[mi], bfr[ni], acc[mi][ni], 0, 0, 0);
    }
    __builtin_amdgcn_s_barrier();
  }
  const int rb = fq * 4;
  if (EPI == 2) {
    #pragma unroll
    for (int mi = 0; mi < 4; ++mi)
      #pragma unroll
      for (int ni = 0; ni < 4; ++ni) {
        int col = n0 + wc * 64 + ni * 16 + fr;
        float bv = bias[col];
        #pragma unroll
        for (int j = 0; j < 4; ++j) {
          int row = m0 + wr * 64 + mi * 16 + rb + j;
          outb[(size_t)row * O + col] = f2b(acc[mi][ni][j] + bv);
        }
      }
  } else {
    // LDS-repack epilogue: As (32 KB) dead after last K-step; C-tile = 16 KB bytes
    unsigned char* ctile = (unsigned char*)&As[0][0];
    #pragma unroll
    for (int mi = 0; mi < 4; ++mi) {
      #pragma unroll
      for (int ni = 0; ni < 4; ++ni) {
        int lcol = wc * 64 + ni * 16 + fr;
        float bv = bias[n0 + lcol];
        #pragma unroll
        for (int j = 0; j < 4; ++j) {
          int lrow = wr * 64 + mi * 16 + rb + j;
          float val = acc[mi][ni][j] + bv;
          if (EPI == 1) val = gelu_f(val);
          ctile[lrow * 128 + lcol] = f2e4(val);
        }
      }
    }
    __builtin_amdgcn_s_barrier();
    const int row = t >> 1, off = (t & 1) * 64;
    const char* src = (const char*)ctile + row * 128 + off;
    unsigned char* dst = out8 + (size_t)(m0 + row) * O + n0 + off;
    #pragma unroll
    for (int q = 0; q < 4; ++q)
      *(u32x4*)(dst + q * 16) = *(const u32x4*)(src + q * 16);
  }
}

// ---------------- fp8 fc2 transposed: out[b,c,n] += g2[c]*(sum_k W2[c,k]*H2[b,n,k] + b2[c]) ----------------
__global__ __launch_bounds__(256) void fc2t8_k(const unsigned char* __restrict__ W2b,
    const unsigned char* __restrict__ H2, const float* __restrict__ b2,
    const float* __restrict__ g2, float* __restrict__ out, int bofs) {
  __shared__ __align__(16) unsigned char As[2][128 * 128];
  __shared__ __align__(16) unsigned char Bs[2][128 * 128];
  const int K = HID2_;
  const int nwg = 8 * gridDim.y;
  const int lid = blockIdx.y * 8 + blockIdx.x;
  const int chunk = nwg >> 3;
  const int swz = (lid & 7) * chunk + (lid >> 3);
  const int n0 = (swz & 7) * 128;
  const int y2 = swz >> 3;
  const int img = y2 / 3, m0 = (y2 % 3) * 128;
  const int t = threadIdx.x, l = t & 63, wv = t >> 6;
  const int wr = wv >> 1, wc = wv & 1;
  const int fr = l & 15, fq = l >> 4;
  const int arow = t >> 3;
  const int acsw = ((t & 7) ^ (arow & 7)) * 16;
  const unsigned char* Ag = W2b + (size_t)(m0 + arow) * K + acsw;
  const unsigned char* Bg = H2 + ((size_t)img * N_ + n0 + arow) * K + acsw;
  f32x4 acc[4][4];
  #pragma unroll
  for (int i = 0; i < 4; ++i)
    #pragma unroll
    for (int j = 0; j < 4; ++j) acc[i][j] = f32x4{0.f, 0.f, 0.f, 0.f};

  auto stage = [&](int buf, int k0) {
    char* Ad = (char*)&As[buf][0] + wv * 1024;
    char* Bd = (char*)&Bs[buf][0] + wv * 1024;
    #pragma unroll
    for (int s = 0; s < 4; ++s) {
      gload_lds16(Ag + (size_t)(s * 32) * K + k0, Ad + s * 4096);
      gload_lds16(Bg + (size_t)(s * 32) * K + k0, Bd + s * 4096);
    }
  };

  const int nt = K >> 7;                            // 18
  stage(0, 0);
  for (int tt = 0; tt < nt; ++tt) {
    const int cur = tt & 1;
    if (tt + 1 < nt) {
      stage(cur ^ 1, (tt + 1) << 7);
      asm volatile("s_waitcnt vmcnt(8)" ::: "memory");
    } else {
      asm volatile("s_waitcnt vmcnt(0)" ::: "memory");
    }
    __builtin_amdgcn_s_barrier();
    #pragma unroll
    for (int kk = 0; kk < 4; ++kk) {
      const int slot = (kk << 1) | (fq >> 1);
      const int sub = (fq & 1) << 3;
      long af[4], bfr[4];
      #pragma unroll
      for (int mi = 0; mi < 4; ++mi) {
        int row = wr * 64 + mi * 16 + fr;
        af[mi] = *(const long*)((const char*)&As[cur][0] + row * 128 +
                                ((slot ^ (row & 7)) << 4) + sub);
      }
      #pragma unroll
      for (int ni = 0; ni < 4; ++ni) {
        int row = wc * 64 + ni * 16 + fr;
        bfr[ni] = *(const long*)((const char*)&Bs[cur][0] + row * 128 +
                                 ((slot ^ (row & 7)) << 4) + sub);
      }
      #pragma unroll
      for (int mi = 0; mi < 4; ++mi)
        #pragma unroll
        for (int ni = 0; ni < 4; ++ni)
          acc[mi][ni] = __builtin_amdgcn_mfma_f32_16x16x32_fp8_fp8(af[mi], bfr[ni], acc[mi][ni], 0, 0, 0);
    }
    __builtin_amdgcn_s_barrier();
  }
  const int rb = fq * 4;
  const size_t obase = ((size_t)(img + bofs) * C_) << 10;
  #pragma unroll
  for (int mi = 0; mi < 4; ++mi) {
    #pragma unroll
    for (int j = 0; j < 4; ++j) {
      int row = m0 + wr * 64 + mi * 16 + rb + j;
      float bv = b2[row], gv = g2[row];
      #pragma unroll
      for (int ni = 0; ni < 4; ++ni) {
        int col = n0 + wc * 64 + ni * 16 + fr;
        size_t oi = obase + ((size_t)row << 10) + col;
        out[oi] = out[oi] + gv * (acc[mi][ni][j] + bv);
      }
    }
  }
}

// ---------------- fused gram + l2norm + temp-scale + softmax -> attn fp8 (B,6,64,64) ----------------
__global__ __launch_bounds__(256) void attn_k(const unsigned char* __restrict__ qkv,
    const float* __restrict__ temp, unsigned char* __restrict__ attn8) {
  __shared__ __align__(16) float Qs[32][68];
  __shared__ __align__(16) float Ks[32][68];
  __shared__ float qinv_s[64], kinv_s[64];
  const int bid = blockIdx.x;           // B*6
  const int b = bid / 6, h = bid % 6;
  const int t = threadIdx.x;
  const unsigned char* qb = qkv + (size_t)b * N_ * QS_ + h * 64;
  const unsigned char* kb = qb + 384;
  const int li = t >> 4, ld = (t & 15) * 4;
  const int d0 = (t >> 4) * 4, e0 = (t & 15) * 4;
  float acc[4][4] = {};
  float ssq = 0.0f;
  for (int n0 = 0; n0 < N_; n0 += 32) {
    __syncthreads();
    #pragma unroll
    for (int rr = 0; rr < 2; ++rr) {
      int i = li + rr * 16;
      unsigned int qv = *(const unsigned int*)(qb + (size_t)(n0 + i) * QS_ + ld);
      unsigned int kv = *(const unsigned int*)(kb + (size_t)(n0 + i) * QS_ + ld);
      float qd[4], kd[4];
      dec4(qv, qd); dec4(kv, kd);
      #pragma unroll
      for (int j = 0; j < 4; ++j) { Qs[i][ld + j] = qd[j]; Ks[i][ld + j] = kd[j]; }
    }
    __syncthreads();
    if (t < 64) {
      #pragma unroll
      for (int i = 0; i < 32; ++i) { float x = Qs[i][t]; ssq += x * x; }
    } else if (t < 128) {
      #pragma unroll
      for (int i = 0; i < 32; ++i) { float x = Ks[i][t - 64]; ssq += x * x; }
    }
    #pragma unroll
    for (int i = 0; i < 32; ++i) {
      f32x4 qv = *(const f32x4*)&Qs[i][d0];
      f32x4 kv = *(const f32x4*)&Ks[i][e0];
      #pragma unroll
      for (int di = 0; di < 4; ++di)
        #pragma unroll
        for (int ei = 0; ei < 4; ++ei) acc[di][ei] += qv[di] * kv[ei];
    }
  }
  if (t < 64) { float nr = sqrtf(ssq); qinv_s[t] = 1.0f / fmaxf(nr, 1e-12f); }
  else if (t < 128) { float nr = sqrtf(ssq); kinv_s[t - 64] = 1.0f / fmaxf(nr, 1e-12f); }
  __syncthreads();
  const float tp = temp[h];
  #pragma unroll
  for (int di = 0; di < 4; ++di) {
    int d = d0 + di;
    float vals[4];
    #pragma unroll
    for (int ei = 0; ei < 4; ++ei) vals[ei] = acc[di][ei] * qinv_s[d] * kinv_s[e0 + ei] * tp;
    float mx = fmaxf(fmaxf(vals[0], vals[1]), fmaxf(vals[2], vals[3]));
    #pragma unroll
    for (int m = 1; m < 16; m <<= 1) mx = fmaxf(mx, __shfl_xor(mx, m));
    float ex[4], s = 0.f;
    #pragma unroll
    for (int ei = 0; ei < 4; ++ei) { ex[ei] = __expf(vals[ei] - mx); s += ex[ei]; }
    #pragma unroll
    for (int m = 1; m < 16; m <<= 1) s += __shfl_xor(s, m);
    float inv = __builtin_amdgcn_rcpf(s);
    unsigned int ov = enc4(ex[0] * inv, ex[1] * inv, ex[2] * inv, ex[3] * inv);
    *(unsigned int*)(attn8 + ((size_t)(b * 6 + h) * 64 + d) * 64 + e0) = ov;
  }
}

// ---------------- dwconv3x3 + BN + SiLU, times vc -> v (fp8), 4ch x 4w per thread ----------------
__global__ __launch_bounds__(192) void dwconv1_k(const unsigned char* __restrict__ xn,
    const float* __restrict__ dwt, const float* __restrict__ dwb,
    const float* __restrict__ bng, const float* __restrict__ bnb,
    const float* __restrict__ bnm, const float* __restrict__ bnv,
    unsigned char* __restrict__ qkv) {
  const int c0 = threadIdx.x * 4;                 // [0,384)
  const int h = blockIdx.y >> 2;
  const int w0 = (blockIdx.y & 3) * 8 + threadIdx.y * 4;
  const int b = blockIdx.z;
  const unsigned char* xb = xn + ((size_t)b * N_ + h * 32) * C_ + c0;
  f32x4 acc[4] = {};
  #pragma unroll
  for (int dy = -1; dy <= 1; ++dy) {
    int hh = h + dy;
    if (hh < 0 || hh >= 32) continue;
    f32x4 xf[6];
    #pragma unroll
    for (int j = 0; j < 6; ++j) {
      int ww = w0 - 1 + j;
      if (ww >= 0 && ww < 32) {
        unsigned int xv = *(const unsigned int*)(xb + (dy * 32 + ww) * C_);
        float d4[4]; dec4(xv, d4);
        xf[j] = f32x4{d4[0], d4[1], d4[2], d4[3]};
      } else xf[j] = f32x4{0.f, 0.f, 0.f, 0.f};
    }
    #pragma unroll
    for (int dx = 0; dx < 3; ++dx) {
      f32x4 wv = *(const f32x4*)(dwt + ((dy + 1) * 3 + dx) * C_ + c0);
      #pragma unroll
      for (int px = 0; px < 4; ++px)
        #pragma unroll
        for (int j = 0; j < 4; ++j) acc[px][j] += xf[dx + px][j] * wv[j];
    }
  }
  f32x4 dbv = *(const f32x4*)(dwb + c0);
  f32x4 mv = *(const f32x4*)(bnm + c0);
  f32x4 vv = *(const f32x4*)(bnv + c0);
  f32x4 gv = *(const f32x4*)(bng + c0);
  f32x4 bv = *(const f32x4*)(bnb + c0);
  f32x4 rs;
  #pragma unroll
  for (int j = 0; j < 4; ++j) rs[j] = rsqrtf(vv[j] + 1e-5f);
  unsigned char* vb = qkv + ((size_t)b * N_ + h * 32 + w0) * QS_ + 768 + c0;
  #pragma unroll
  for (int px = 0; px < 4; ++px) {
    unsigned int vcv = *(const unsigned int*)(vb + px * QS_);
    float vd[4]; dec4(vcv, vd);
    float o4[4];
    #pragma unroll
    for (int j = 0; j < 4; ++j) {
      float u = (acc[px][j] + dbv[j] - mv[j]) * rs[j] * gv[j] + bv[j];
      float si = u * sigmoid_f(u);
      o4[j] = si * vd[j];
    }
    *(unsigned int*)(vb + px * QS_) = enc4(o4[0], o4[1], o4[2], o4[3]);
  }
}

// ---------------- xo[b,n,h*64+d] = sum_e attn[b,h,d,e] * v[b,n,h*64+e] (fp8 MFMA) ----------------
__global__ __launch_bounds__(256) void xo_k(const unsigned char* __restrict__ qkv,
    const unsigned char* __restrict__ attn, unsigned char* __restrict__ xo) {
  const int bid = blockIdx.x;           // B*6*16
  const int b = bid / 96, r = bid % 96, h = r / 16, m0 = (r % 16) * 64;
  const int t = threadIdx.x, wv = t >> 6, l = t & 63;
  const int n0 = m0 + wv * 16;
  const int fr = l & 15, fq = l >> 4;
  const unsigned char* vb = qkv + (size_t)b * N_ * QS_ + 768 + h * 64;
  const unsigned char* ab = attn + (size_t)(b * 6 + h) * 4096;
  f32x4 acc[4];
  #pragma unroll
  for (int i = 0; i < 4; ++i) acc[i] = f32x4{0.f, 0.f, 0.f, 0.f};
  #pragma unroll
  for (int k0 = 0; k0 < 64; k0 += 32) {
    long af = *(const long*)(vb + (size_t)(n0 + fr) * QS_ + k0 + fq * 8);
    #pragma unroll
    for (int ni = 0; ni < 4; ++ni) {
      long bfr = *(const long*)(ab + (ni * 16 + fr) * 64 + k0 + fq * 8);
      acc[ni] = __builtin_amdgcn_mfma_f32_16x16x32_fp8_fp8(af, bfr, acc[ni], 0, 0, 0);
    }
  }
  const int rb = fq * 4;
  #pragma unroll
  for (int ni = 0; ni < 4; ++ni)
    #pragma unroll
    for (int j = 0; j < 4; ++j) {
      int row = n0 + rb + j;
      xo[((size_t)b * N_ + row) * C_ + h * 64 + ni * 16 + fr] = f2e4(acc[ni][j]);
    }
}

// ---------------- faithful swapaxes residual: out = x + scramble(gamma1*y), f32 NCHW ----------------
__global__ __launch_bounds__(256) void resid1_k(const float* __restrict__ x,
    const unsigned short* __restrict__ y, const float* __restrict__ g1,
    float* __restrict__ xnew) {
  __shared__ unsigned short yp[32][36];
  __shared__ float g1s[32];
  const int bid = blockIdx.x;           // B*C
  const int b = bid / C_, c2 = bid % C_;
  const int hsrc = c2 / 12, cs0 = (c2 % 12) * 32;
  const int t = threadIdx.x;
  {
    int wq = t >> 3, h4 = (t & 7) * 4;
    u16x4 vv = *(const u16x4*)(y + ((size_t)b * N_ + hsrc * 32 + wq) * C_ + cs0 + h4);
    *(u16x4*)&yp[wq][h4] = vv;          // yp[w][h2]
  }
  if (t < 32) g1s[t] = g1[cs0 + t];
  __syncthreads();
  int h2 = t >> 3, w0 = (t & 7) * 4;
  size_t base = (((size_t)b * C_ + c2) << 10) + h2 * 32 + w0;
  f32x4 xv = *(const f32x4*)(x + base);
  f32x4 ov;
  #pragma unroll
  for (int i = 0; i < 4; ++i) ov[i] = xv[i] + g1s[h2] * b2f(yp[w0 + i][h2]);
  *(f32x4*)(xnew + base) = ov;
}

// ---------------- dwconv3x3 (hid) + GELU, fp8 in/out, 4ch x 4w per thread ----------------
__global__ __launch_bounds__(192) void dwconv2_k(const unsigned char* __restrict__ h1,
    const float* __restrict__ dwt, const float* __restrict__ dwb,
    unsigned char* __restrict__ h2) {
  const int c0 = (blockIdx.x * 192 + threadIdx.x) * 4;   // < 2304
  const int h = blockIdx.y >> 3, w0 = (blockIdx.y & 7) * 4;
  const int b = blockIdx.z;
  const unsigned char* xb = h1 + ((size_t)b * N_ + h * 32) * HID2_ + c0;
  f32x4 acc[4] = {};
  #pragma unroll
  for (int dy = -1; dy <= 1; ++dy) {
    int hh = h + dy;
    if (hh < 0 || hh >= 32) continue;
    f32x4 xf[6];
    #pragma unroll
    for (int j = 0; j < 6; ++j) {
      int ww = w0 - 1 + j;
      if (ww >= 0 && ww < 32) {
        unsigned int xv = *(const unsigned int*)(xb + (dy * 32 + ww) * HID2_);
        float d4[4]; dec4(xv, d4);
        xf[j] = f32x4{d4[0], d4[1], d4[2], d4[3]};
      } else xf[j] = f32x4{0.f, 0.f, 0.f, 0.f};
    }
    #pragma unroll
    for (int dx = 0; dx < 3; ++dx) {
      f32x4 wv = *(const f32x4*)(dwt + ((dy + 1) * 3 + dx) * HID2_ + c0);
      #pragma unroll
      for (int px = 0; px < 4; ++px)
        #pragma unroll
        for (int j = 0; j < 4; ++j) acc[px][j] += xf[dx + px][j] * wv[j];
    }
  }
  f32x4 dbv = *(const f32x4*)(dwb + c0);
  unsigned char* ob = h2 + ((size_t)b * N_ + h * 32 + w0) * HID2_ + c0;
  #pragma unroll
  for (int px = 0; px < 4; ++px) {
    unsigned int ov = enc4(gelu_f(acc[px][0] + dbv[0]), gelu_f(acc[px][1] + dbv[1]),
                           gelu_f(acc[px][2] + dbv[2]), gelu_f(acc[px][3] + dbv[3]));
    *(unsigned int*)(ob + px * HID2_) = ov;
  }
}

// ================================================================
extern "C" void kernel_launch(void* const* d_in, const int* in_sizes, int n_in,
                              void* d_out, int out_size, void* d_ws, size_t ws_size,
                              hipStream_t stream) {
  (void)in_sizes; (void)n_in; (void)out_size;
  const float* x    = (const float*)d_in[0];
  const float* posw = (const float*)d_in[1];
  const float* posb = (const float*)d_in[2];
  const float* ln1w = (const float*)d_in[3];
  const float* ln1b = (const float*)d_in[4];
  const float* q_w  = (const float*)d_in[5];
  const float* q_b  = (const float*)d_in[6];
  const float* k_w  = (const float*)d_in[7];
  const float* k_b  = (const float*)d_in[8];
  const float* v_w  = (const float*)d_in[9];
  const float* v_b  = (const float*)d_in[10];
  const float* dw_w = (const float*)d_in[11];
  const float* dw_b = (const float*)d_in[12];
  const float* bn_g = (const float*)d_in[13];
  const float* bn_b = (const float*)d_in[14];
  const float* bn_m = (const float*)d_in[15];
  const float* bn_v = (const float*)d_in[16];
  const float* temp = (const float*)d_in[17];
  const float* pj_w = (const float*)d_in[18];
  const float* pj_b = (const float*)d_in[19];
  const float* g1   = (const float*)d_in[20];
  const float* ln2w = (const float*)d_in[21];
  const float* ln2b = (const float*)d_in[22];
  const float* w1   = (const float*)d_in[23];
  const float* b1   = (const float*)d_in[24];
  const float* mdw  = (const float*)d_in[25];
  const float* mdb  = (const float*)d_in[26];
  const float* w2   = (const float*)d_in[27];
  const float* b2   = (const float*)d_in[28];
  const float* g2   = (const float*)d_in[29];
  float* out = (float*)d_out;           // also serves as XNEW (f32 B,C,H,W residual)

  char* ws = (char*)d_ws;
  size_t off = 0;
  auto alloc = [&](size_t bytes) { size_t o = off; off += (bytes + 255) & ~(size_t)255; return o; };
  const size_t TOK = (size_t)B_ * N_;            // 32768

  size_t oWQKV = alloc(442368), oWP = alloc(147456);        // fp8
  size_t oW1 = alloc(884736), oW2 = alloc(884736);          // fp8
  size_t oDT1 = alloc(9 * C_ * 4), oDT2 = alloc(9 * HID2_ * 4);
  size_t oBQKV = alloc(1152 * 4);
  size_t oFEAT = alloc(65536 * 4);
  size_t oPOS  = alloc((size_t)N_ * C_ * 4);
  size_t oATT  = alloc((size_t)B_ * 6 * 4096);              // fp8
  size_t oXN2  = alloc(TOK * C_);                // fp8 xn2 (survives into MLP)
  size_t oQKV  = alloc(TOK * QS_);               // fp8 37.7 MB -- dead before MLP
  size_t oXN = alloc(TOK * C_);                  // fp8 xn
  size_t oSC = alloc(TOK * C_);                  // fp8 xo
  size_t oSA = alloc(TOK * C_ * 2);              // bf16 y (proj out)

  // MLP H1/H2 (fp8) overlay the dead QKV+XN+SC+SA region plus remaining workspace.
  const size_t perImg = (size_t)N_ * HID2_;      // 2,359,296 B (fp8)
  size_t avail = (ws_size > oQKV + 512) ? (ws_size - oQKV - 512) : 0;
  int CH = (int)(avail / (2 * perImg));
  if (CH < 1) CH = 1;
  if (CH > 32) CH = 32;
  size_t oH1 = oQKV;
  size_t oH2 = oQKV + (size_t)CH * perImg;

  unsigned char* WQKV = (unsigned char*)(ws + oWQKV);
  unsigned char* WP = (unsigned char*)(ws + oWP);
  unsigned char* W1 = (unsigned char*)(ws + oW1);
  unsigned char* W2 = (unsigned char*)(ws + oW2);
  float* DT1 = (float*)(ws + oDT1);
  float* DT2 = (float*)(ws + oDT2);
  float* BQKV = (float*)(ws + oBQKV);
  float* FEAT = (float*)(ws + oFEAT);
  float* POS  = (float*)(ws + oPOS);
  unsigned char* ATT = (unsigned char*)(ws + oATT);
  unsigned char* XN2 = (unsigned char*)(ws + oXN2);
  unsigned char* QKV = (unsigned char*)(ws + oQKV);
  unsigned char* XN = (unsigned char*)(ws + oXN);
  unsigned char* SC = (unsigned char*)(ws + oSC);
  unsigned short* SA = (unsigned short*)(ws + oSA);
  unsigned char* H1 = (unsigned char*)(ws + oH1);
  unsigned char* H2 = (unsigned char*)(ws + oH2);

  // one-shot prep (weights, transposes, biases, fourier)
  prep_k<<<9571, 256, 0, stream>>>(q_w, k_w, v_w, pj_w, w1, w2, dw_w, mdw,
                                   q_b, k_b, v_b, WQKV, WP, W1, W2, DT1, DT2, BQKV, FEAT);
  pos_k<<<1024, 384, 0, stream>>>(FEAT, posw, posb, POS);
  // LN1 (x + pos) -> XN fp8
  ln_k<1><<<1024, 256, 0, stream>>>(x, POS, ln1w, ln1b, XN);
  // fused q|k|vc projection (fp8) -> QKV fp8
  gemm8_k<0><<<dim3(9, 256), 256, 0, stream>>>(XN, WQKV, BQKV, QKV, nullptr, 384, 1152);
  // gram + l2norm + softmax -> ATT fp8
  attn_k<<<192, 256, 0, stream>>>(QKV, temp, ATT);
  // v = silu(bn(dwconv(xn))) * vc, in place in QKV cols 768..
  dwconv1_k<<<dim3(1, 128, 32), dim3(96, 2), 0, stream>>>(XN, DT1, dw_b, bn_g, bn_b, bn_m, bn_v, QKV);
  // xo = attn @ v -> SC fp8
  xo_k<<<3072, 256, 0, stream>>>(QKV, ATT, SC);
  // proj (fp8) -> SA bf16 (xn dead)
  gemm8_k<2><<<dim3(3, 256), 256, 0, stream>>>(SC, WP, pj_b, nullptr, SA, 384, 384);
  // residual 1 with swapaxes scramble -> out (f32 NCHW)
  resid1_k<<<12288, 256, 0, stream>>>(x, SA, g1, out);
  // LN2 (reads out) -> XN2 fp8 (QKV/XN/SC/SA now dead)
  ln_k<0><<<1024, 256, 0, stream>>>(out, nullptr, ln2w, ln2b, XN2);
  // MLP branch (all fp8), chunked over batch
  for (int b0 = 0; b0 < B_; b0 += CH) {
    int cb = (b0 + CH <= B_) ? CH : (B_ - b0);
    const unsigned char* xn2c = XN2 + (size_t)b0 * N_ * C_;
    gemm8_k<1><<<dim3(18, cb * 8), 256, 0, stream>>>(xn2c, W1, b1, H1, nullptr, 384, 2304);
    dwconv2_k<<<dim3(3, 256, cb), 192, 0, stream>>>(H1, DT2, mdb, H2);
    fc2t8_k<<<dim3(8, 3 * cb), 256, 0, stream>>>(W2, H2, b2, g2, out, b0);
  }
}

// Round 16
// 452.240 us; speedup vs baseline: 1.0494x; 1.0238x over previous
//
#include <hip/hip_runtime.h>
#include <cstdint>
#include <cstddef>
#include <cmath>

#define DI __device__ __forceinline__

typedef __attribute__((ext_vector_type(2))) float f32x2;
typedef __attribute__((ext_vector_type(4))) float f32x4;
typedef __attribute__((ext_vector_type(4))) unsigned short u16x4;

constexpr int B_ = 32, C_ = 384, N_ = 1024, HID2_ = 2304, QS_ = 1152;

DI unsigned short f2b(float f) {
  union { float f; unsigned int u; } v; v.f = f;
  unsigned int u = v.u;
  return (unsigned short)((u + 0x7FFFu + ((u >> 16) & 1u)) >> 16);
}
DI float b2f(unsigned short h) {
  union { unsigned int u; float f; } v; v.u = ((unsigned int)h) << 16;
  return v.f;
}
DI float sigmoid_f(float x) { return __builtin_amdgcn_rcpf(1.0f + __expf(-x)); }
// fast GELU: branch outputs scaled by gamma=1e-6 -> ~1e-8 abs error contribution
DI float gelu_f(float x) { return x * sigmoid_f(1.702f * x); }

DI void gload_lds16(const void* g, void* l) {
  __builtin_amdgcn_global_load_lds(
      (const __attribute__((address_space(1))) void*)g,
      (__attribute__((address_space(3))) void*)l, 16, 0, 0);
}

// ---------------- fp8 e4m3 (OCP) helpers; both branches are gamma=1e-6 scaled ----------------
#if __has_builtin(__builtin_amdgcn_cvt_pk_fp8_f32) && __has_builtin(__builtin_amdgcn_cvt_pk_f32_fp8)
#define HW_FP8 1
#else
#define HW_FP8 0
#endif

DI unsigned char f2e4_sw(float x) {
  float a = fabsf(x);
  unsigned char s = (x < 0.f) ? 0x80 : 0;
  if (!(a >= 0.0009765625f)) return s;
  if (a >= 448.f) return s | 0x7E;
  int e; float m = frexpf(a, &e);
  m *= 2.f; e -= 1;
  if (e < -6) {
    int q = (int)rintf(a * 512.f);
    if (q > 7) return s | 0x08;
    return s | (unsigned char)q;
  }
  int mi = (int)rintf((m - 1.f) * 8.f);
  if (mi == 8) { mi = 0; e += 1; }
  if (e > 8) return s | 0x7E;
  return s | (unsigned char)(((e + 7) << 3) | mi);
}
DI float e42f_sw(unsigned char h) {
  int e = (h >> 3) & 0xF, m = h & 7;
  float v;
  if (e == 0) v = (float)m * 0.001953125f;
  else { union { unsigned u; float f; } w; w.u = (unsigned)((e + 120) << 23) | ((unsigned)m << 20); v = w.f; }
  return (h & 0x80) ? -v : v;
}
DI unsigned char f2e4(float x) {
#if HW_FP8
  int r = __builtin_amdgcn_cvt_pk_fp8_f32(x, x, 0, false);
  return (unsigned char)(r & 0xFF);
#else
  return f2e4_sw(x);
#endif
}
DI unsigned int enc4(float a, float b, float c, float d) {
#if HW_FP8
  int r = 0;
  r = __builtin_amdgcn_cvt_pk_fp8_f32(a, b, r, false);
  r = __builtin_amdgcn_cvt_pk_fp8_f32(c, d, r, true);
  return (unsigned int)r;
#else
  return (unsigned)f2e4(a) | ((unsigned)f2e4(b) << 8) | ((unsigned)f2e4(c) << 16) | ((unsigned)f2e4(d) << 24);
#endif
}
DI void dec4(unsigned int v, float* o) {
#if HW_FP8
  f32x2 lo = __builtin_amdgcn_cvt_pk_f32_fp8((int)v, false);
  f32x2 hi = __builtin_amdgcn_cvt_pk_f32_fp8((int)v, true);
  o[0] = lo[0]; o[1] = lo[1]; o[2] = hi[0]; o[3] = hi[1];
#else
  o[0] = e42f_sw(v & 0xFF); o[1] = e42f_sw((v >> 8) & 0xFF);
  o[2] = e42f_sw((v >> 16) & 0xFF); o[3] = e42f_sw((v >> 24) & 0xFF);
#endif
}

// ---------------- one-shot prep: all weights -> fp8, dw transpose, bias concat, fourier ----------------
__global__ void prep_k(const float* __restrict__ q_w, const float* __restrict__ k_w,
    const float* __restrict__ vc_w, const float* __restrict__ pj_w,
    const float* __restrict__ w1, const float* __restrict__ w2,
    const float* __restrict__ dw_w, const float* __restrict__ mdw,
    const float* __restrict__ q_b, const float* __restrict__ k_b, const float* __restrict__ v_b,
    unsigned char* __restrict__ WQKV, unsigned char* __restrict__ WP,
    unsigned char* __restrict__ W1, unsigned char* __restrict__ W2,
    float* __restrict__ DT1, float* __restrict__ DT2,
    float* __restrict__ BQKV, float* __restrict__ feat) {
  int i = blockIdx.x * 256 + threadIdx.x;
  if (i < 442368) {                                    // WQKV (1152 x 384) fp8
    int o = i / 384, c = i % 384;
    float v = (o < 384) ? q_w[o * 384 + c] : (o < 768) ? k_w[(o - 384) * 384 + c]
                                                       : vc_w[(o - 768) * 384 + c];
    WQKV[i] = f2e4(v); return;
  }
  i -= 442368;
  if (i < 147456) { WP[i] = f2e4(pj_w[i]); return; }
  i -= 147456;
  if (i < 884736) { W1[i] = f2e4(w1[i]); return; }
  i -= 884736;
  if (i < 884736) { W2[i] = f2e4(w2[i]); return; }
  i -= 884736;
  if (i < 3456)  { int c = i / 9, k = i % 9; DT1[k * C_ + c] = dw_w[i]; return; }
  i -= 3456;
  if (i < 20736) { int c = i / 9, k = i % 9; DT2[k * HID2_ + c] = mdw[i]; return; }
  i -= 20736;
  if (i < 1152)  { BQKV[i] = (i < 384) ? q_b[i] : (i < 768) ? k_b[i - 384] : v_b[i - 768]; return; }
  i -= 1152;
  if (i < 65536) {                                     // fourier features (N x 64)
    int n = i >> 6, j = i & 63;
    int h = n >> 5, w = n & 31;
    const float scale = 6.283185307179586f;
    float e = (j < 32) ? (float)(h + 1) / (32.0f + 1e-6f) * scale
                       : (float)(w + 1) / (32.0f + 1e-6f) * scale;
    int jj = j & 31;
    float dt = powf(10000.0f, (float)(jj >> 1) * (1.0f / 16.0f));
    float arg = e / dt;
    feat[i] = (jj & 1) ? cosf(arg) : sinf(arg);
  }
}

// ---------------- pos[n][c] = feat[n][:] . pos_w[c][:] + pos_b[c] ----------------
__global__ __launch_bounds__(384) void pos_k(const float* __restrict__ feat,
    const float* __restrict__ pw, const float* __restrict__ pb, float* __restrict__ pos) {
  __shared__ float fs[64];
  int n = blockIdx.x, c = threadIdx.x;
  if (c < 64) fs[c] = feat[n * 64 + c];
  __syncthreads();
  float s = pb[c];
  #pragma unroll
  for (int j = 0; j < 64; ++j) s += fs[j] * pw[c * 64 + j];
  pos[(size_t)n * C_ + c] = s;
}

// ---------------- LayerNorm over C, input (B,C,N) f32, output (B,N,C) fp8 ----------------
template<int HASPOS>
__global__ __launch_bounds__(256) void ln_k(const float* __restrict__ xin,
    const float* __restrict__ pos, const float* __restrict__ lw,
    const float* __restrict__ lb, unsigned char* __restrict__ out8) {
  __shared__ float tile[C_ * 33];
  int bid = blockIdx.x;                 // B * (N/32)
  int b = bid >> 5, n0 = (bid & 31) << 5;
  int t = threadIdx.x;
  const float* xb = xin + (size_t)b * C_ * N_;
  #pragma unroll
  for (int i = 0; i < 48; ++i) {
    int f = t + 256 * i;
    int c = f >> 5, nn = f & 31;
    tile[c * 33 + nn] = xb[(size_t)c * N_ + n0 + nn];
  }
  __syncthreads();
  int wv = t >> 6, l = t & 63;
  for (int tk = 0; tk < 8; ++tk) {
    int tn = wv * 8 + tk;
    float v[6];
    #pragma unroll
    for (int i = 0; i < 6; ++i) {
      int c = l + 64 * i;
      float x = tile[c * 33 + tn];
      if (HASPOS) x += pos[(size_t)(n0 + tn) * C_ + c];
      v[i] = x;
    }
    float s = v[0] + v[1] + v[2] + v[3] + v[4] + v[5];
    #pragma unroll
    for (int m = 1; m < 64; m <<= 1) s += __shfl_xor(s, m);
    float mean = s * (1.0f / 384.0f);
    float q = 0.f;
    #pragma unroll
    for (int i = 0; i < 6; ++i) { float d = v[i] - mean; q += d * d; }
    #pragma unroll
    for (int m = 1; m < 64; m <<= 1) q += __shfl_xor(q, m);
    float rstd = rsqrtf(q * (1.0f / 384.0f) + 1e-6f);
    #pragma unroll
    for (int i = 0; i < 6; ++i) {
      int c = l + 64 * i;
      out8[((size_t)b * N_ + n0 + tn) * C_ + c] = f2e4((v[i] - mean) * rstd * lw[c] + lb[c]);
    }
  }
}

// ---------------- fp8 MFMA GEMM: out(M,O) = A(M,K) @ Wt(O,K)^T + bias ----------------
// BK=128 fp8, both-sides XOR swizzle, counted-vmcnt 2-phase staging (proven R13 template).
// EPI 0: fp8 out. EPI 1: fp8 GELU out. EPI 2: bf16 out.
template<int EPI>
__global__ __launch_bounds__(256) void gemm8_k(const unsigned char* __restrict__ A,
    const unsigned char* __restrict__ Wt, const float* __restrict__ bias,
    unsigned char* __restrict__ out8, unsigned short* __restrict__ outb,
    int K, int O) {
  __shared__ __align__(16) unsigned char As[2][128 * 128];
  __shared__ __align__(16) unsigned char Bs[2][128 * 128];
  const int gx = gridDim.x;
  const int nwg = gx * gridDim.y;
  const int lid = blockIdx.y * gx + blockIdx.x;
  const int chunk = nwg >> 3;
  const int swz = (lid & 7) * chunk + (lid >> 3);
  const int m0 = (swz / gx) * 128, n0 = (swz % gx) * 128;
  const int t = threadIdx.x, l = t & 63, wv = t >> 6;
  const int wr = wv >> 1, wc = wv & 1;
  const int fr = l & 15, fq = l >> 4;
  const int arow = t >> 3;
  const int acsw = ((t & 7) ^ (arow & 7)) * 16;
  const unsigned char* Ag = A + (size_t)(m0 + arow) * K + acsw;
  const unsigned char* Bg = Wt + (size_t)(n0 + arow) * K + acsw;
  f32x4 acc[4][4];
  #pragma unroll
  for (int i = 0; i < 4; ++i)
    #pragma unroll
    for (int j = 0; j < 4; ++j) acc[i][j] = f32x4{0.f, 0.f, 0.f, 0.f};

  auto stage = [&](int buf, int k0) {
    char* Ad = (char*)&As[buf][0] + wv * 1024;
    char* Bd = (char*)&Bs[buf][0] + wv * 1024;
    #pragma unroll
    for (int s = 0; s < 4; ++s) {
      gload_lds16(Ag + (size_t)(s * 32) * K + k0, Ad + s * 4096);
      gload_lds16(Bg + (size_t)(s * 32) * K + k0, Bd + s * 4096);
    }
  };

  const int nt = K >> 7;
  stage(0, 0);
  for (int tt = 0; tt < nt; ++tt) {
    const int cur = tt & 1;
    if (tt + 1 < nt) {
      stage(cur ^ 1, (tt + 1) << 7);
      asm volatile("s_waitcnt vmcnt(8)" ::: "memory");
    } else {
      asm volatile("s_waitcnt vmcnt(0)" ::: "memory");
    }
    __builtin_amdgcn_s_barrier();
    #pragma unroll
    for (int kk = 0; kk < 4; ++kk) {
      const int slot = (kk << 1) | (fq >> 1);
      const int sub = (fq & 1) << 3;
      long af[4], bfr[4];
      #pragma unroll
      for (int mi = 0; mi < 4; ++mi) {
        int row = wr * 64 + mi * 16 + fr;
        af[mi] = *(const long*)((const char*)&As[cur][0] + row * 128 +
                                ((slot ^ (row & 7)) << 4) + sub);
      }
      #pragma unroll
      for (int ni = 0; ni < 4; ++ni) {
        int row = wc * 64 + ni * 16 + fr;
        bfr[ni] = *(const long*)((const char*)&Bs[cur][0] + row * 128 +
                                 ((slot ^ (row & 7)) << 4) + sub);
      }
      #pragma unroll
      for (int mi = 0; mi < 4; ++mi)
        #pragma unroll
        for (int ni = 0; ni < 4; ++ni)
          acc[mi][ni] = __builtin_amdgcn_mfma_f32_16x16x32_fp8_fp8(af[mi], bfr[ni], acc[mi][ni], 0, 0, 0);
    }
    __builtin_amdgcn_s_barrier();
  }
  const int rb = fq * 4;
  #pragma unroll
  for (int mi = 0; mi < 4; ++mi) {
    #pragma unroll
    for (int ni = 0; ni < 4; ++ni) {
      int col = n0 + wc * 64 + ni * 16 + fr;
      float bv = bias[col];
      #pragma unroll
      for (int j = 0; j < 4; ++j) {
        int row = m0 + wr * 64 + mi * 16 + rb + j;
        float val = acc[mi][ni][j] + bv;
        if (EPI == 0)      out8[(size_t)row * O + col] = f2e4(val);
        else if (EPI == 1) out8[(size_t)row * O + col] = f2e4(gelu_f(val));
        else               outb[(size_t)row * O + col] = f2b(val);
      }
    }
  }
}

// ---------------- fp8 fc2 transposed: out[b,c,n] += g2[c]*(sum_k W2[c,k]*H2[b,n,k] + b2[c]) ----------------
__global__ __launch_bounds__(256) void fc2t8_k(const unsigned char* __restrict__ W2b,
    const unsigned char* __restrict__ H2, const float* __restrict__ b2,
    const float* __restrict__ g2, float* __restrict__ out, int bofs) {
  __shared__ __align__(16) unsigned char As[2][128 * 128];
  __shared__ __align__(16) unsigned char Bs[2][128 * 128];
  const int K = HID2_;
  const int nwg = 8 * gridDim.y;
  const int lid = blockIdx.y * 8 + blockIdx.x;
  const int chunk = nwg >> 3;
  const int swz = (lid & 7) * chunk + (lid >> 3);
  const int n0 = (swz & 7) * 128;
  const int y2 = swz >> 3;
  const int img = y2 / 3, m0 = (y2 % 3) * 128;
  const int t = threadIdx.x, l = t & 63, wv = t >> 6;
  const int wr = wv >> 1, wc = wv & 1;
  const int fr = l & 15, fq = l >> 4;
  const int arow = t >> 3;
  const int acsw = ((t & 7) ^ (arow & 7)) * 16;
  const unsigned char* Ag = W2b + (size_t)(m0 + arow) * K + acsw;
  const unsigned char* Bg = H2 + ((size_t)img * N_ + n0 + arow) * K + acsw;
  f32x4 acc[4][4];
  #pragma unroll
  for (int i = 0; i < 4; ++i)
    #pragma unroll
    for (int j = 0; j < 4; ++j) acc[i][j] = f32x4{0.f, 0.f, 0.f, 0.f};

  auto stage = [&](int buf, int k0) {
    char* Ad = (char*)&As[buf][0] + wv * 1024;
    char* Bd = (char*)&Bs[buf][0] + wv * 1024;
    #pragma unroll
    for (int s = 0; s < 4; ++s) {
      gload_lds16(Ag + (size_t)(s * 32) * K + k0, Ad + s * 4096);
      gload_lds16(Bg + (size_t)(s * 32) * K + k0, Bd + s * 4096);
    }
  };

  const int nt = K >> 7;                            // 18
  stage(0, 0);
  for (int tt = 0; tt < nt; ++tt) {
    const int cur = tt & 1;
    if (tt + 1 < nt) {
      stage(cur ^ 1, (tt + 1) << 7);
      asm volatile("s_waitcnt vmcnt(8)" ::: "memory");
    } else {
      asm volatile("s_waitcnt vmcnt(0)" ::: "memory");
    }
    __builtin_amdgcn_s_barrier();
    #pragma unroll
    for (int kk = 0; kk < 4; ++kk) {
      const int slot = (kk << 1) | (fq >> 1);
      const int sub = (fq & 1) << 3;
      long af[4], bfr[4];
      #pragma unroll
      for (int mi = 0; mi < 4; ++mi) {
        int row = wr * 64 + mi * 16 + fr;
        af[mi] = *(const long*)((const char*)&As[cur][0] + row * 128 +
                                ((slot ^ (row & 7)) << 4) + sub);
      }
      #pragma unroll
      for (int ni = 0; ni < 4; ++ni) {
        int row = wc * 64 + ni * 16 + fr;
        bfr[ni] = *(const long*)((const char*)&Bs[cur][0] + row * 128 +
                                 ((slot ^ (row & 7)) << 4) + sub);
      }
      #pragma unroll
      for (int mi = 0; mi < 4; ++mi)
        #pragma unroll
        for (int ni = 0; ni < 4; ++ni)
          acc[mi][ni] = __builtin_amdgcn_mfma_f32_16x16x32_fp8_fp8(af[mi], bfr[ni], acc[mi][ni], 0, 0, 0);
    }
    __builtin_amdgcn_s_barrier();
  }
  const int rb = fq * 4;
  const size_t obase = ((size_t)(img + bofs) * C_) << 10;
  #pragma unroll
  for (int mi = 0; mi < 4; ++mi) {
    #pragma unroll
    for (int j = 0; j < 4; ++j) {
      int row = m0 + wr * 64 + mi * 16 + rb + j;
      float bv = b2[row], gv = g2[row];
      #pragma unroll
      for (int ni = 0; ni < 4; ++ni) {
        int col = n0 + wc * 64 + ni * 16 + fr;
        size_t oi = obase + ((size_t)row << 10) + col;
        out[oi] = out[oi] + gv * (acc[mi][ni][j] + bv);
      }
    }
  }
}

// ---------------- fused gram + l2norm + temp-scale + softmax -> attn fp8 (B,6,64,64) ----------------
__global__ __launch_bounds__(256) void attn_k(const unsigned char* __restrict__ qkv,
    const float* __restrict__ temp, unsigned char* __restrict__ attn8) {
  __shared__ __align__(16) float Qs[32][68];
  __shared__ __align__(16) float Ks[32][68];
  __shared__ float qinv_s[64], kinv_s[64];
  const int bid = blockIdx.x;           // B*6
  const int b = bid / 6, h = bid % 6;
  const int t = threadIdx.x;
  const unsigned char* qb = qkv + (size_t)b * N_ * QS_ + h * 64;
  const unsigned char* kb = qb + 384;
  const int li = t >> 4, ld = (t & 15) * 4;
  const int d0 = (t >> 4) * 4, e0 = (t & 15) * 4;
  float acc[4][4] = {};
  float ssq = 0.0f;
  for (int n0 = 0; n0 < N_; n0 += 32) {
    __syncthreads();
    #pragma unroll
    for (int rr = 0; rr < 2; ++rr) {
      int i = li + rr * 16;
      unsigned int qv = *(const unsigned int*)(qb + (size_t)(n0 + i) * QS_ + ld);
      unsigned int kv = *(const unsigned int*)(kb + (size_t)(n0 + i) * QS_ + ld);
      float qd[4], kd[4];
      dec4(qv, qd); dec4(kv, kd);
      #pragma unroll
      for (int j = 0; j < 4; ++j) { Qs[i][ld + j] = qd[j]; Ks[i][ld + j] = kd[j]; }
    }
    __syncthreads();
    if (t < 64) {
      #pragma unroll
      for (int i = 0; i < 32; ++i) { float x = Qs[i][t]; ssq += x * x; }
    } else if (t < 128) {
      #pragma unroll
      for (int i = 0; i < 32; ++i) { float x = Ks[i][t - 64]; ssq += x * x; }
    }
    #pragma unroll
    for (int i = 0; i < 32; ++i) {
      f32x4 qv = *(const f32x4*)&Qs[i][d0];
      f32x4 kv = *(const f32x4*)&Ks[i][e0];
      #pragma unroll
      for (int di = 0; di < 4; ++di)
        #pragma unroll
        for (int ei = 0; ei < 4; ++ei) acc[di][ei] += qv[di] * kv[ei];
    }
  }
  if (t < 64) { float nr = sqrtf(ssq); qinv_s[t] = 1.0f / fmaxf(nr, 1e-12f); }
  else if (t < 128) { float nr = sqrtf(ssq); kinv_s[t - 64] = 1.0f / fmaxf(nr, 1e-12f); }
  __syncthreads();
  const float tp = temp[h];
  #pragma unroll
  for (int di = 0; di < 4; ++di) {
    int d = d0 + di;
    float vals[4];
    #pragma unroll
    for (int ei = 0; ei < 4; ++ei) vals[ei] = acc[di][ei] * qinv_s[d] * kinv_s[e0 + ei] * tp;
    float mx = fmaxf(fmaxf(vals[0], vals[1]), fmaxf(vals[2], vals[3]));
    #pragma unroll
    for (int m = 1; m < 16; m <<= 1) mx = fmaxf(mx, __shfl_xor(mx, m));
    float ex[4], s = 0.f;
    #pragma unroll
    for (int ei = 0; ei < 4; ++ei) { ex[ei] = __expf(vals[ei] - mx); s += ex[ei]; }
    #pragma unroll
    for (int m = 1; m < 16; m <<= 1) s += __shfl_xor(s, m);
    float inv = __builtin_amdgcn_rcpf(s);
    unsigned int ov = enc4(ex[0] * inv, ex[1] * inv, ex[2] * inv, ex[3] * inv);
    *(unsigned int*)(attn8 + ((size_t)(b * 6 + h) * 64 + d) * 64 + e0) = ov;
  }
}

// ---------------- dwconv3x3 + BN + SiLU, times vc -> v (fp8), 4ch x 4w per thread ----------------
__global__ __launch_bounds__(192) void dwconv1_k(const unsigned char* __restrict__ xn,
    const float* __restrict__ dwt, const float* __restrict__ dwb,
    const float* __restrict__ bng, const float* __restrict__ bnb,
    const float* __restrict__ bnm, const float* __restrict__ bnv,
    unsigned char* __restrict__ qkv) {
  const int c0 = threadIdx.x * 4;                 // [0,384)
  const int h = blockIdx.y >> 2;
  const int w0 = (blockIdx.y & 3) * 8 + threadIdx.y * 4;
  const int b = blockIdx.z;
  const unsigned char* xb = xn + ((size_t)b * N_ + h * 32) * C_ + c0;
  f32x4 acc[4] = {};
  #pragma unroll
  for (int dy = -1; dy <= 1; ++dy) {
    int hh = h + dy;
    if (hh < 0 || hh >= 32) continue;
    f32x4 xf[6];
    #pragma unroll
    for (int j = 0; j < 6; ++j) {
      int ww = w0 - 1 + j;
      if (ww >= 0 && ww < 32) {
        unsigned int xv = *(const unsigned int*)(xb + (dy * 32 + ww) * C_);
        float d4[4]; dec4(xv, d4);
        xf[j] = f32x4{d4[0], d4[1], d4[2], d4[3]};
      } else xf[j] = f32x4{0.f, 0.f, 0.f, 0.f};
    }
    #pragma unroll
    for (int dx = 0; dx < 3; ++dx) {
      f32x4 wv = *(const f32x4*)(dwt + ((dy + 1) * 3 + dx) * C_ + c0);
      #pragma unroll
      for (int px = 0; px < 4; ++px)
        #pragma unroll
        for (int j = 0; j < 4; ++j) acc[px][j] += xf[dx + px][j] * wv[j];
    }
  }
  f32x4 dbv = *(const f32x4*)(dwb + c0);
  f32x4 mv = *(const f32x4*)(bnm + c0);
  f32x4 vv = *(const f32x4*)(bnv + c0);
  f32x4 gv = *(const f32x4*)(bng + c0);
  f32x4 bv = *(const f32x4*)(bnb + c0);
  f32x4 rs;
  #pragma unroll
  for (int j = 0; j < 4; ++j) rs[j] = rsqrtf(vv[j] + 1e-5f);
  unsigned char* vb = qkv + ((size_t)b * N_ + h * 32 + w0) * QS_ + 768 + c0;
  #pragma unroll
  for (int px = 0; px < 4; ++px) {
    unsigned int vcv = *(const unsigned int*)(vb + px * QS_);
    float vd[4]; dec4(vcv, vd);
    float o4[4];
    #pragma unroll
    for (int j = 0; j < 4; ++j) {
      float u = (acc[px][j] + dbv[j] - mv[j]) * rs[j] * gv[j] + bv[j];
      float si = u * sigmoid_f(u);
      o4[j] = si * vd[j];
    }
    *(unsigned int*)(vb + px * QS_) = enc4(o4[0], o4[1], o4[2], o4[3]);
  }
}

// ---------------- xo[b,n,h*64+d] = sum_e attn[b,h,d,e] * v[b,n,h*64+e] (fp8 MFMA) ----------------
__global__ __launch_bounds__(256) void xo_k(const unsigned char* __restrict__ qkv,
    const unsigned char* __restrict__ attn, unsigned char* __restrict__ xo) {
  const int bid = blockIdx.x;           // B*6*16
  const int b = bid / 96, r = bid % 96, h = r / 16, m0 = (r % 16) * 64;
  const int t = threadIdx.x, wv = t >> 6, l = t & 63;
  const int n0 = m0 + wv * 16;
  const int fr = l & 15, fq = l >> 4;
  const unsigned char* vb = qkv + (size_t)b * N_ * QS_ + 768 + h * 64;
  const unsigned char* ab = attn + (size_t)(b * 6 + h) * 4096;
  f32x4 acc[4];
  #pragma unroll
  for (int i = 0; i < 4; ++i) acc[i] = f32x4{0.f, 0.f, 0.f, 0.f};
  #pragma unroll
  for (int k0 = 0; k0 < 64; k0 += 32) {
    long af = *(const long*)(vb + (size_t)(n0 + fr) * QS_ + k0 + fq * 8);
    #pragma unroll
    for (int ni = 0; ni < 4; ++ni) {
      long bfr = *(const long*)(ab + (ni * 16 + fr) * 64 + k0 + fq * 8);
      acc[ni] = __builtin_amdgcn_mfma_f32_16x16x32_fp8_fp8(af, bfr, acc[ni], 0, 0, 0);
    }
  }
  const int rb = fq * 4;
  #pragma unroll
  for (int ni = 0; ni < 4; ++ni)
    #pragma unroll
    for (int j = 0; j < 4; ++j) {
      int row = n0 + rb + j;
      xo[((size_t)b * N_ + row) * C_ + h * 64 + ni * 16 + fr] = f2e4(acc[ni][j]);
    }
}

// ---------------- faithful swapaxes residual: out = x + scramble(gamma1*y), f32 NCHW ----------------
__global__ __launch_bounds__(256) void resid1_k(const float* __restrict__ x,
    const unsigned short* __restrict__ y, const float* __restrict__ g1,
    float* __restrict__ xnew) {
  __shared__ unsigned short yp[32][36];
  __shared__ float g1s[32];
  const int bid = blockIdx.x;           // B*C
  const int b = bid / C_, c2 = bid % C_;
  const int hsrc = c2 / 12, cs0 = (c2 % 12) * 32;
  const int t = threadIdx.x;
  {
    int wq = t >> 3, h4 = (t & 7) * 4;
    u16x4 vv = *(const u16x4*)(y + ((size_t)b * N_ + hsrc * 32 + wq) * C_ + cs0 + h4);
    *(u16x4*)&yp[wq][h4] = vv;          // yp[w][h2]
  }
  if (t < 32) g1s[t] = g1[cs0 + t];
  __syncthreads();
  int h2 = t >> 3, w0 = (t & 7) * 4;
  size_t base = (((size_t)b * C_ + c2) << 10) + h2 * 32 + w0;
  f32x4 xv = *(const f32x4*)(x + base);
  f32x4 ov;
  #pragma unroll
  for (int i = 0; i < 4; ++i) ov[i] = xv[i] + g1s[h2] * b2f(yp[w0 + i][h2]);
  *(f32x4*)(xnew + base) = ov;
}

// ---------------- dwconv3x3 (hid) + GELU, fp8 in/out, 4ch x 4w per thread ----------------
__global__ __launch_bounds__(192) void dwconv2_k(const unsigned char* __restrict__ h1,
    const float* __restrict__ dwt, const float* __restrict__ dwb,
    unsigned char* __restrict__ h2) {
  const int c0 = (blockIdx.x * 192 + threadIdx.x) * 4;   // < 2304
  const int h = blockIdx.y >> 3, w0 = (blockIdx.y & 7) * 4;
  const int b = blockIdx.z;
  const unsigned char* xb = h1 + ((size_t)b * N_ + h * 32) * HID2_ + c0;
  f32x4 acc[4] = {};
  #pragma unroll
  for (int dy = -1; dy <= 1; ++dy) {
    int hh = h + dy;
    if (hh < 0 || hh >= 32) continue;
    f32x4 xf[6];
    #pragma unroll
    for (int j = 0; j < 6; ++j) {
      int ww = w0 - 1 + j;
      if (ww >= 0 && ww < 32) {
        unsigned int xv = *(const unsigned int*)(xb + (dy * 32 + ww) * HID2_);
        float d4[4]; dec4(xv, d4);
        xf[j] = f32x4{d4[0], d4[1], d4[2], d4[3]};
      } else xf[j] = f32x4{0.f, 0.f, 0.f, 0.f};
    }
    #pragma unroll
    for (int dx = 0; dx < 3; ++dx) {
      f32x4 wv = *(const f32x4*)(dwt + ((dy + 1) * 3 + dx) * HID2_ + c0);
      #pragma unroll
      for (int px = 0; px < 4; ++px)
        #pragma unroll
        for (int j = 0; j < 4; ++j) acc[px][j] += xf[dx + px][j] * wv[j];
    }
  }
  f32x4 dbv = *(const f32x4*)(dwb + c0);
  unsigned char* ob = h2 + ((size_t)b * N_ + h * 32 + w0) * HID2_ + c0;
  #pragma unroll
  for (int px = 0; px < 4; ++px) {
    unsigned int ov = enc4(gelu_f(acc[px][0] + dbv[0]), gelu_f(acc[px][1] + dbv[1]),
                           gelu_f(acc[px][2] + dbv[2]), gelu_f(acc[px][3] + dbv[3]));
    *(unsigned int*)(ob + px * HID2_) = ov;
  }
}

// ================================================================
extern "C" void kernel_launch(void* const* d_in, const int* in_sizes, int n_in,
                              void* d_out, int out_size, void* d_ws, size_t ws_size,
                              hipStream_t stream) {
  (void)in_sizes; (void)n_in; (void)out_size;
  const float* x    = (const float*)d_in[0];
  const float* posw = (const float*)d_in[1];
  const float* posb = (const float*)d_in[2];
  const float* ln1w = (const float*)d_in[3];
  const float* ln1b = (const float*)d_in[4];
  const float* q_w  = (const float*)d_in[5];
  const float* q_b  = (const float*)d_in[6];
  const float* k_w  = (const float*)d_in[7];
  const float* k_b  = (const float*)d_in[8];
  const float* v_w  = (const float*)d_in[9];
  const float* v_b  = (const float*)d_in[10];
  const float* dw_w = (const float*)d_in[11];
  const float* dw_b = (const float*)d_in[12];
  const float* bn_g = (const float*)d_in[13];
  const float* bn_b = (const float*)d_in[14];
  const float* bn_m = (const float*)d_in[15];
  const float* bn_v = (const float*)d_in[16];
  const float* temp = (const float*)d_in[17];
  const float* pj_w = (const float*)d_in[18];
  const float* pj_b = (const float*)d_in[19];
  const float* g1   = (const float*)d_in[20];
  const float* ln2w = (const float*)d_in[21];
  const float* ln2b = (const float*)d_in[22];
  const float* w1   = (const float*)d_in[23];
  const float* b1   = (const float*)d_in[24];
  const float* mdw  = (const float*)d_in[25];
  const float* mdb  = (const float*)d_in[26];
  const float* w2   = (const float*)d_in[27];
  const float* b2   = (const float*)d_in[28];
  const float* g2   = (const float*)d_in[29];
  float* out = (float*)d_out;           // also serves as XNEW (f32 B,C,H,W residual)

  char* ws = (char*)d_ws;
  size_t off = 0;
  auto alloc = [&](size_t bytes) { size_t o = off; off += (bytes + 255) & ~(size_t)255; return o; };
  const size_t TOK = (size_t)B_ * N_;            // 32768

  size_t oWQKV = alloc(442368), oWP = alloc(147456);        // fp8
  size_t oW1 = alloc(884736), oW2 = alloc(884736);          // fp8
  size_t oDT1 = alloc(9 * C_ * 4), oDT2 = alloc(9 * HID2_ * 4);
  size_t oBQKV = alloc(1152 * 4);
  size_t oFEAT = alloc(65536 * 4);
  size_t oPOS  = alloc((size_t)N_ * C_ * 4);
  size_t oATT  = alloc((size_t)B_ * 6 * 4096);              // fp8
  size_t oXN2  = alloc(TOK * C_);                // fp8 xn2 (survives into MLP)
  size_t oQKV  = alloc(TOK * QS_);               // fp8 37.7 MB -- dead before MLP
  size_t oXN = alloc(TOK * C_);                  // fp8 xn
  size_t oSC = alloc(TOK * C_);                  // fp8 xo
  size_t oSA = alloc(TOK * C_ * 2);              // bf16 y (proj out)

  // MLP H1/H2 (fp8) overlay the dead QKV+XN+SC+SA region plus remaining workspace.
  const size_t perImg = (size_t)N_ * HID2_;      // 2,359,296 B (fp8)
  size_t avail = (ws_size > oQKV + 512) ? (ws_size - oQKV - 512) : 0;
  int CH = (int)(avail / (2 * perImg));
  if (CH < 1) CH = 1;
  if (CH > 32) CH = 32;
  size_t oH1 = oQKV;
  size_t oH2 = oQKV + (size_t)CH * perImg;

  unsigned char* WQKV = (unsigned char*)(ws + oWQKV);
  unsigned char* WP = (unsigned char*)(ws + oWP);
  unsigned char* W1 = (unsigned char*)(ws + oW1);
  unsigned char* W2 = (unsigned char*)(ws + oW2);
  float* DT1 = (float*)(ws + oDT1);
  float* DT2 = (float*)(ws + oDT2);
  float* BQKV = (float*)(ws + oBQKV);
  float* FEAT = (float*)(ws + oFEAT);
  float* POS  = (float*)(ws + oPOS);
  unsigned char* ATT = (unsigned char*)(ws + oATT);
  unsigned char* XN2 = (unsigned char*)(ws + oXN2);
  unsigned char* QKV = (unsigned char*)(ws + oQKV);
  unsigned char* XN = (unsigned char*)(ws + oXN);
  unsigned char* SC = (unsigned char*)(ws + oSC);
  unsigned short* SA = (unsigned short*)(ws + oSA);
  unsigned char* H1 = (unsigned char*)(ws + oH1);
  unsigned char* H2 = (unsigned char*)(ws + oH2);

  // one-shot prep (weights, transposes, biases, fourier)
  prep_k<<<9571, 256, 0, stream>>>(q_w, k_w, v_w, pj_w, w1, w2, dw_w, mdw,
                                   q_b, k_b, v_b, WQKV, WP, W1, W2, DT1, DT2, BQKV, FEAT);
  pos_k<<<1024, 384, 0, stream>>>(FEAT, posw, posb, POS);
  // LN1 (x + pos) -> XN fp8
  ln_k<1><<<1024, 256, 0, stream>>>(x, POS, ln1w, ln1b, XN);
  // fused q|k|vc projection (fp8) -> QKV fp8
  gemm8_k<0><<<dim3(9, 256), 256, 0, stream>>>(XN, WQKV, BQKV, QKV, nullptr, 384, 1152);
  // gram + l2norm + softmax -> ATT fp8
  attn_k<<<192, 256, 0, stream>>>(QKV, temp, ATT);
  // v = silu(bn(dwconv(xn))) * vc, in place in QKV cols 768..
  dwconv1_k<<<dim3(1, 128, 32), dim3(96, 2), 0, stream>>>(XN, DT1, dw_b, bn_g, bn_b, bn_m, bn_v, QKV);
  // xo = attn @ v -> SC fp8
  xo_k<<<3072, 256, 0, stream>>>(QKV, ATT, SC);
  // proj (fp8) -> SA bf16 (xn dead)
  gemm8_k<2><<<dim3(3, 256), 256, 0, stream>>>(SC, WP, pj_b, nullptr, SA, 384, 384);
  // residual 1 with swapaxes scramble -> out (f32 NCHW)
  resid1_k<<<12288, 256, 0, stream>>>(x, SA, g1, out);
  // LN2 (reads out) -> XN2 fp8 (QKV/XN/SC/SA now dead)
  ln_k<0><<<1024, 256, 0, stream>>>(out, nullptr, ln2w, ln2b, XN2);
  // MLP branch (all fp8), chunked over batch
  for (int b0 = 0; b0 < B_; b0 += CH) {
    int cb = (b0 + CH <= B_) ? CH : (B_ - b0);
    const unsigned char* xn2c = XN2 + (size_t)b0 * N_ * C_;
    gemm8_k<1><<<dim3(18, cb * 8), 256, 0, stream>>>(xn2c, W1, b1, H1, nullptr, 384, 2304);
    dwconv2_k<<<dim3(3, 256, cb), 192, 0, stream>>>(H1, DT2, mdb, H2);
    fc2t8_k<<<dim3(8, 3 * cb), 256, 0, stream>>>(W2, H2, b2, g2, out, b0);
  }
}